// Round 3
// baseline (582.029 us; speedup 1.0000x reference)
//
#include <hip/hip_runtime.h>
#include <cstddef>

// Problem constants (reference: B=32, NDOC=4, L=512, E=512)
#define BATCH 32
#define NB    128
#define LL    512
#define EE    512
#define SCALE 0.044194173824159216f
#define NEG_INF -1e9f

typedef __attribute__((ext_vector_type(4))) float f32x4;
typedef __attribute__((ext_vector_type(8))) short s16x8;          // 8 bf16 (4 VGPRs) MFMA frag
typedef __attribute__((ext_vector_type(4))) unsigned short u16x4;

__device__ __forceinline__ unsigned short f2b(float f) {          // f32 -> bf16 RNE
    unsigned u = __float_as_uint(f);
    u += 0x7FFFu + ((u >> 16) & 1u);
    return (unsigned short)(u >> 16);
}
__device__ __forceinline__ float b2f(unsigned short h) {
    return __uint_as_float(((unsigned)h) << 16);
}

// async global->LDS, 16B per lane. LDS dest = wave-uniform base + lane*16.
__device__ __forceinline__ void gld_lds16(const unsigned short* g, unsigned short* l) {
    __builtin_amdgcn_global_load_lds(
        (const __attribute__((address_space(1))) void*)g,
        (__attribute__((address_space(3))) void*)l, 16, 0, 0);
}

// ---------------------------------------------------------------------------
// Converters: x1 -> bf16; x2 -> bf16 (row) + bf16 transposed; fw -> fw^T bf16
// ---------------------------------------------------------------------------
__global__ __launch_bounds__(256) void k_cvt_x1(
    const float* __restrict__ x1, unsigned short* __restrict__ x1bf)
{
    const size_t idx = (size_t)blockIdx.x * 256 + threadIdx.x;
    f32x4 v = *(const f32x4*)(x1 + idx * 4);
    u16x4 o = { f2b(v[0]), f2b(v[1]), f2b(v[2]), f2b(v[3]) };
    *(u16x4*)(x1bf + idx * 4) = o;
}

__global__ __launch_bounds__(256) void k_cvt_x2(
    const float* __restrict__ x2,
    unsigned short* __restrict__ x2bf, unsigned short* __restrict__ x2t)
{
    __shared__ float T[64][65];
    const int i = blockIdx.z, kb = blockIdx.y * 64, eb = blockIdx.x * 64;
    const float* src = x2 + (size_t)i * LL * EE;
    unsigned short* db = x2bf + (size_t)i * LL * EE;
    unsigned short* dt = x2t  + (size_t)i * LL * EE;
    const int t = threadIdx.x, r16 = t >> 4, c4 = (t & 15) * 4;
#pragma unroll
    for (int p = 0; p < 4; ++p) {
        int row = p * 16 + r16;
        f32x4 v = *(const f32x4*)(src + (size_t)(kb + row) * EE + eb + c4);
        T[row][c4] = v[0]; T[row][c4+1] = v[1]; T[row][c4+2] = v[2]; T[row][c4+3] = v[3];
        u16x4 o = { f2b(v[0]), f2b(v[1]), f2b(v[2]), f2b(v[3]) };
        *(u16x4*)(db + (size_t)(kb + row) * EE + eb + c4) = o;
    }
    __syncthreads();
#pragma unroll
    for (int p = 0; p < 4; ++p) {
        int erow = p * 16 + r16;
        u16x4 o = { f2b(T[c4][erow]), f2b(T[c4+1][erow]),
                    f2b(T[c4+2][erow]), f2b(T[c4+3][erow]) };
        *(u16x4*)(dt + (size_t)(eb + erow) * LL + kb + c4) = o;   // dt[e][k]=src[k][e]
    }
}

// fw [1024][512] -> fwt[e][j'] bf16 with K-interleave j' = (j<512) ? 2j : 2(j-512)+1
// (matches Cbuf's interleaved [diff,prod] pair layout; GEMM result invariant).
__global__ __launch_bounds__(256) void k_cvt_fw(
    const float* __restrict__ fw, unsigned short* __restrict__ fwt)
{
    __shared__ float T[64][65];
    const int jb = blockIdx.y * 64, eb = blockIdx.x * 64;
    const int t = threadIdx.x, r16 = t >> 4, c4 = (t & 15) * 4;
#pragma unroll
    for (int p = 0; p < 4; ++p) {
        int row = p * 16 + r16;
        f32x4 v = *(const f32x4*)(fw + (size_t)(jb + row) * EE + eb + c4);
        T[row][c4] = v[0]; T[row][c4+1] = v[1]; T[row][c4+2] = v[2]; T[row][c4+3] = v[3];
    }
    __syncthreads();
#pragma unroll
    for (int p = 0; p < 4; ++p) {
        int erow = p * 16 + r16;
#pragma unroll
        for (int k = 0; k < 4; ++k) {
            int jold = jb + c4 + k;
            int jn = (jold < 512) ? (2 * jold) : (2 * (jold - 512) + 1);
            fwt[(size_t)(eb + erow) * 1024 + jn] = f2b(T[c4 + k][erow]);
        }
    }
}

// ---------------------------------------------------------------------------
// K1 (fused): scores GEMM -> in-block softmax -> PV GEMM.
// One block = one batch i x 128 q-rows x full k-range (512).
// T3-min 2-phase schedule: double-buffered global_load_lds staging issued at
// TOP of each K-step (prefetch flies under MFMA), ONE __syncthreads per step
// (its vmcnt/lgkm drain provides all cross-wave ordering; race-free).
// LDS 160KB: [0,128K) scores-staging dbuf (80K) then P[128][512] swizzled;
// [128K,160K) softmax reduce arrays then PV B-stage dbuf. Time-disjoint.
// ---------------------------------------------------------------------------
__global__ __launch_bounds__(1024, 4) void k_attn(
    const unsigned short* __restrict__ x1bf,
    const unsigned short* __restrict__ x2bf,
    const unsigned short* __restrict__ x2t,
    const int* __restrict__ x1_len, const int* __restrict__ x2_len,
    float* __restrict__ attn, unsigned short* __restrict__ Cbuf)
{
    __shared__ __align__(16) char smem[163840];                 // 160 KB
    unsigned short* A0 = (unsigned short*)smem;                 // [128][32] 8KB
    unsigned short* B0 = (unsigned short*)(smem + 8192);        // [512][32] 32KB
    unsigned short* A1 = (unsigned short*)(smem + 40960);       // 8KB
    unsigned short* B1 = (unsigned short*)(smem + 49152);       // 32KB -> 80KB
    // P lives at smem[0..128K), swizzled; addressed via byte offsets.
    unsigned short* V0 = (unsigned short*)(smem + 131072);      // [256][32] 16KB
    unsigned short* V1 = (unsigned short*)(smem + 147456);      // 16KB
    float* rowred = (float*)(smem + 131072);                    // [8][128] (aliases V0)
    float* rowst  = (float*)(smem + 131072 + 4096);             // [128]

    const int i  = blockIdx.x;
    const int q0 = blockIdx.y * 128;
    const unsigned short* Ag = x1bf + (size_t)(i & 31) * LL * EE;
    const unsigned short* Bg = x2bf + (size_t)i * LL * EE;
    const unsigned short* Vg = x2t  + (size_t)i * LL * EE;
    const int t = threadIdx.x, lane = t & 63;
    const int w = t >> 6;
    const int m = lane & 15, quad = lane >> 4;
    const int lrow = lane >> 2, lcol = (lane & 3) * 8;
    const int wrow = w >> 3, wcol = w & 7;                      // scores: 2x8 waves

    f32x4 acc[4][4];
#pragma unroll
    for (int r = 0; r < 4; ++r)
#pragma unroll
        for (int c = 0; c < 4; ++c) acc[r][c] = (f32x4){0.f, 0.f, 0.f, 0.f};

    // ---- Phase 1: scores GEMM over e, dbuf single-barrier ----
    // prologue: stage e0=0 into buf0
    if (w < 8)
        gld_lds16(Ag + (size_t)(q0 + w * 16 + lrow) * EE + lcol, &A0[w * 512]);
    gld_lds16(Bg + (size_t)((2 * w) * 16 + lrow) * EE + lcol, &B0[(2 * w) * 512]);
    gld_lds16(Bg + (size_t)((2 * w + 1) * 16 + lrow) * EE + lcol, &B0[(2 * w + 1) * 512]);
    __syncthreads();

    for (int it = 0; it < 16; ++it) {
        unsigned short* Ac = (it & 1) ? A1 : A0;
        unsigned short* Bc = (it & 1) ? B1 : B0;
        if (it < 15) {                                          // stage next slice
            unsigned short* An = (it & 1) ? A0 : A1;
            unsigned short* Bn = (it & 1) ? B0 : B1;
            const int e0n = (it + 1) * 32;
            if (w < 8)
                gld_lds16(Ag + (size_t)(q0 + w * 16 + lrow) * EE + e0n + lcol, &An[w * 512]);
            gld_lds16(Bg + (size_t)((2 * w) * 16 + lrow) * EE + e0n + lcol, &Bn[(2 * w) * 512]);
            gld_lds16(Bg + (size_t)((2 * w + 1) * 16 + lrow) * EE + e0n + lcol, &Bn[(2 * w + 1) * 512]);
        }
        s16x8 af[4], bfr[4];
#pragma unroll
        for (int rt = 0; rt < 4; ++rt)
            af[rt] = *(const s16x8*)&Ac[(wrow * 64 + rt * 16 + m) * 32 + quad * 8];
#pragma unroll
        for (int ct = 0; ct < 4; ++ct)
            bfr[ct] = *(const s16x8*)&Bc[(wcol * 64 + ct * 16 + m) * 32 + quad * 8];
#pragma unroll
        for (int rt = 0; rt < 4; ++rt)
#pragma unroll
            for (int ct = 0; ct < 4; ++ct)
                acc[rt][ct] = __builtin_amdgcn_mfma_f32_16x16x32_bf16(
                    af[rt], bfr[ct], acc[rt][ct], 0, 0, 0);
        __syncthreads();                                        // drains vm+lgkm: next
    }                                                           // slice landed, reads done

    const int qlen = x1_len[i & 31];
    const int klen = x2_len[i];

    // ---- mask + scale in place ----
#pragma unroll
    for (int rt = 0; rt < 4; ++rt)
#pragma unroll
        for (int reg = 0; reg < 4; ++reg) {
            const int l = q0 + wrow * 64 + rt * 16 + quad * 4 + reg;
            const bool qok = l < qlen;
#pragma unroll
            for (int ct = 0; ct < 4; ++ct) {
                const int k = wcol * 64 + ct * 16 + m;
                acc[rt][ct][reg] = (qok && k < klen) ? acc[rt][ct][reg] * SCALE : NEG_INF;
            }
        }

    // ---- row max: per-wave 64-col partial -> LDS -> 8-way reduce ----
#pragma unroll
    for (int rt = 0; rt < 4; ++rt)
#pragma unroll
        for (int reg = 0; reg < 4; ++reg) {
            float v = fmaxf(fmaxf(acc[rt][0][reg], acc[rt][1][reg]),
                            fmaxf(acc[rt][2][reg], acc[rt][3][reg]));
            v = fmaxf(v, __shfl_xor(v, 1));
            v = fmaxf(v, __shfl_xor(v, 2));
            v = fmaxf(v, __shfl_xor(v, 4));
            v = fmaxf(v, __shfl_xor(v, 8));
            if (m == 0)
                rowred[wcol * 128 + wrow * 64 + rt * 16 + quad * 4 + reg] = v;
        }
    __syncthreads();
    if (t < 128) {
        float mx = rowred[t];
#pragma unroll
        for (int c = 1; c < 8; ++c) mx = fmaxf(mx, rowred[c * 128 + t]);
        rowst[t] = mx;
    }
    __syncthreads();

    // ---- exp + row sum ----
#pragma unroll
    for (int rt = 0; rt < 4; ++rt)
#pragma unroll
        for (int reg = 0; reg < 4; ++reg) {
            const int lloc = wrow * 64 + rt * 16 + quad * 4 + reg;
            const float mx = rowst[lloc];
            float s = 0.f;
#pragma unroll
            for (int ct = 0; ct < 4; ++ct) {
                float p = __expf(acc[rt][ct][reg] - mx);
                acc[rt][ct][reg] = p;
                s += p;
            }
            s += __shfl_xor(s, 1);
            s += __shfl_xor(s, 2);
            s += __shfl_xor(s, 4);
            s += __shfl_xor(s, 8);
            if (m == 0) rowred[wcol * 128 + lloc] = s;
        }
    __syncthreads();
    if (t < 128) {
        float s = 0.f;
#pragma unroll
        for (int c = 0; c < 8; ++c) s += rowred[c * 128 + t];
        rowst[t] = 1.0f / s;
    }
    __syncthreads();

    // ---- normalize: write attn f32 (output) + P bf16 (LDS, swizzled) ----
    float* op = attn + (size_t)i * LL * LL;
#pragma unroll
    for (int rt = 0; rt < 4; ++rt)
#pragma unroll
        for (int reg = 0; reg < 4; ++reg) {
            const int lloc = wrow * 64 + rt * 16 + quad * 4 + reg;
            const float inv = rowst[lloc];
#pragma unroll
            for (int ct = 0; ct < 4; ++ct) {
                const int k = wcol * 64 + ct * 16 + m;
                float p = acc[rt][ct][reg] * inv;
                op[(size_t)(q0 + lloc) * LL + k] = p;
                unsigned off = (unsigned)(lloc * 1024 + k * 2) ^ (unsigned)((lloc & 7) << 4);
                *(unsigned short*)(smem + off) = f2b(p);
            }
        }
    __syncthreads();                                           // P complete; rowst dead

    // ---- Phase 2: PV GEMM, two e-halves of 256, dbuf single-barrier ----
    const int pwr = w >> 2, pwc = w & 3;                       // PV: 4x4 waves
    unsigned short* Cb = Cbuf + (size_t)i * LL * 1024;
#pragma unroll
    for (int eh = 0; eh < 2; ++eh) {
        f32x4 acc2[2][4];
#pragma unroll
        for (int r = 0; r < 2; ++r)
#pragma unroll
            for (int c = 0; c < 4; ++c) acc2[r][c] = (f32x4){0.f, 0.f, 0.f, 0.f};

        // prologue: stage k0=0 into V0
        gld_lds16(Vg + (size_t)(eh * 256 + w * 16 + lrow) * LL + lcol, &V0[w * 512]);
        __syncthreads();

        for (int kt = 0; kt < 16; ++kt) {
            const int k0 = kt * 32;
            unsigned short* Vc = (kt & 1) ? V1 : V0;
            if (kt < 15) {
                unsigned short* Vn = (kt & 1) ? V0 : V1;
                gld_lds16(Vg + (size_t)(eh * 256 + w * 16 + lrow) * LL + k0 + 32 + lcol,
                          &Vn[w * 512]);
            }
            s16x8 paf[2], pbf[4];
#pragma unroll
            for (int rt = 0; rt < 2; ++rt) {
                const int lr = pwr * 32 + rt * 16 + m;
                unsigned off = (unsigned)(lr * 1024 + (k0 + quad * 8) * 2)
                               ^ (unsigned)((lr & 7) << 4);
                paf[rt] = *(const s16x8*)(smem + off);
            }
#pragma unroll
            for (int ct = 0; ct < 4; ++ct)
                pbf[ct] = *(const s16x8*)&Vc[(pwc * 64 + ct * 16 + m) * 32 + quad * 8];
#pragma unroll
            for (int rt = 0; rt < 2; ++rt)
#pragma unroll
                for (int ct = 0; ct < 4; ++ct)
                    acc2[rt][ct] = __builtin_amdgcn_mfma_f32_16x16x32_bf16(
                        paf[rt], pbf[ct], acc2[rt][ct], 0, 0, 0);
            __syncthreads();
        }

        // epilogue: Cbuf[l][2e]=x1-att, [2e+1]=x1*att
#pragma unroll
        for (int rt = 0; rt < 2; ++rt)
#pragma unroll
            for (int reg = 0; reg < 4; ++reg) {
                const int l = q0 + pwr * 32 + rt * 16 + quad * 4 + reg;
#pragma unroll
                for (int ct = 0; ct < 4; ++ct) {
                    const int e = eh * 256 + pwc * 64 + ct * 16 + m;
                    float att = acc2[rt][ct][reg];
                    float xv  = b2f(Ag[(size_t)l * EE + e]);
                    unsigned pr = (unsigned)f2b(xv - att) | ((unsigned)f2b(xv * att) << 16);
                    *(unsigned*)(Cb + (size_t)l * 1024 + 2 * e) = pr;
                }
            }
    }
}

// ---------------------------------------------------------------------------
// K4: fus = relu(Cbuf @ fw + b) with per-l-tile mean/max pooling partials.
// Same T3-min dbuf single-barrier schedule.
// ---------------------------------------------------------------------------
__global__ __launch_bounds__(256) void k_fuse_mfma(
    const unsigned short* __restrict__ Cbuf,
    const unsigned short* __restrict__ fwt,
    const float* __restrict__ fb,
    float* __restrict__ pmean, float* __restrict__ pmax)
{
    __shared__ unsigned short Al[2][128 * 32];
    __shared__ unsigned short Bl[2][128 * 32];
    __shared__ float psum[2][128];
    __shared__ float pmx[2][128];
    const int i  = blockIdx.x;
    const int lt = blockIdx.y >> 2;
    const int e0 = (blockIdx.y & 3) * 128;
    const unsigned short* Ab = Cbuf + ((size_t)i * LL + lt * 128) * 1024;
    const int t = threadIdx.x, lane = t & 63;
    const int w = t >> 6, wrow = w >> 1, wcol = w & 1;
    const int m = lane & 15, quad = lane >> 4;
    const int lrow = lane >> 2, lcol = (lane & 3) * 8;

    float bias[4];
#pragma unroll
    for (int ct = 0; ct < 4; ++ct) bias[ct] = fb[e0 + wcol * 64 + ct * 16 + m];
    float csum[4] = {0.f, 0.f, 0.f, 0.f};
    float cmax[4] = {-3e38f, -3e38f, -3e38f, -3e38f};

    f32x4 acc[4][4];
#pragma unroll
    for (int r = 0; r < 4; ++r)
#pragma unroll
        for (int c = 0; c < 4; ++c) acc[r][c] = (f32x4){0.f, 0.f, 0.f, 0.f};

    // prologue: stage j0=0 into buf0
#pragma unroll
    for (int c = 0; c < 2; ++c) {
        const int s = c * 4 + w;
        gld_lds16(Ab + (size_t)(s * 16 + lrow) * 1024 + lcol, &Al[0][s * 512]);
        gld_lds16(fwt + (size_t)(e0 + s * 16 + lrow) * 1024 + lcol, &Bl[0][s * 512]);
    }
    __syncthreads();

    for (int it = 0; it < 32; ++it) {
        const int cur = it & 1;
        if (it < 31) {
            const int j0n = (it + 1) * 32;
#pragma unroll
            for (int c = 0; c < 2; ++c) {
                const int s = c * 4 + w;
                gld_lds16(Ab + (size_t)(s * 16 + lrow) * 1024 + j0n + lcol,
                          &Al[cur ^ 1][s * 512]);
                gld_lds16(fwt + (size_t)(e0 + s * 16 + lrow) * 1024 + j0n + lcol,
                          &Bl[cur ^ 1][s * 512]);
            }
        }
        s16x8 af[4], bfr[4];
#pragma unroll
        for (int rt = 0; rt < 4; ++rt)
            af[rt] = *(const s16x8*)&Al[cur][(wrow * 64 + rt * 16 + m) * 32 + quad * 8];
#pragma unroll
        for (int ct = 0; ct < 4; ++ct)
            bfr[ct] = *(const s16x8*)&Bl[cur][(wcol * 64 + ct * 16 + m) * 32 + quad * 8];
#pragma unroll
        for (int rt = 0; rt < 4; ++rt)
#pragma unroll
            for (int ct = 0; ct < 4; ++ct)
                acc[rt][ct] = __builtin_amdgcn_mfma_f32_16x16x32_bf16(
                    af[rt], bfr[ct], acc[rt][ct], 0, 0, 0);
        __syncthreads();
    }
#pragma unroll
    for (int rt = 0; rt < 4; ++rt)
#pragma unroll
        for (int reg = 0; reg < 4; ++reg)
#pragma unroll
            for (int ct = 0; ct < 4; ++ct) {
                float f = fmaxf(acc[rt][ct][reg] + bias[ct], 0.f);
                csum[ct] += f;
                cmax[ct] = fmaxf(cmax[ct], f);
            }
#pragma unroll
    for (int ct = 0; ct < 4; ++ct) {
        csum[ct] += __shfl_xor(csum[ct], 16);
        csum[ct] += __shfl_xor(csum[ct], 32);
        cmax[ct] = fmaxf(cmax[ct], __shfl_xor(cmax[ct], 16));
        cmax[ct] = fmaxf(cmax[ct], __shfl_xor(cmax[ct], 32));
    }
    if (quad == 0) {
#pragma unroll
        for (int ct = 0; ct < 4; ++ct) {
            psum[wrow][wcol * 64 + ct * 16 + m] = csum[ct];
            pmx[wrow][wcol * 64 + ct * 16 + m] = cmax[ct];
        }
    }
    __syncthreads();
    if (t < 128) {
        float s  = psum[0][t] + psum[1][t];
        float mx = fmaxf(pmx[0][t], pmx[1][t]);
        pmean[((size_t)i * 4 + lt) * EE + e0 + t] = s;     // raw sum over 128 l's
        pmax[((size_t)i * 4 + lt) * EE + e0 + t]  = mx;
    }
}

// ---------------------------------------------------------------------------
// K5a: split-K partial GEMM for the output head; reduces the 4 l-tile pooling
// partials inline while loading the pooled vector.
// ---------------------------------------------------------------------------
__global__ __launch_bounds__(256) void k_out_split(
    const float* __restrict__ pmean, const float* __restrict__ pmax,
    const float* __restrict__ ow, float* __restrict__ partial)
{
    __shared__ float ps[256];
    const int kc = blockIdx.x;
    const int b  = blockIdx.y;
    const int t  = threadIdx.x;
    const int j  = kc * 256 + t;
    const int jj = (j < 2048) ? j : j - 2048;
    const int ii = 4 * b + (jj >> 9);
    const int e  = jj & 511;
    float v;
    if (j < 2048) {
        const float* bp = pmean + (size_t)ii * 4 * EE + e;
        v = (bp[0] + bp[512] + bp[1024] + bp[1536]) * (1.0f / 512.0f);
    } else {
        const float* bp = pmax + (size_t)ii * 4 * EE + e;
        v = fmaxf(fmaxf(bp[0], bp[512]), fmaxf(bp[1024], bp[1536]));
    }
    ps[t] = v;
    __syncthreads();
    f32x4 acc = {0.f, 0.f, 0.f, 0.f};
    const float* wp = ow + (size_t)kc * 256 * 1024 + t * 4;
#pragma unroll 8
    for (int q = 0; q < 256; ++q) {
        f32x4 w4 = *(const f32x4*)(wp + (size_t)q * 1024);
        float p = ps[q];
        acc[0] = fmaf(p, w4[0], acc[0]);
        acc[1] = fmaf(p, w4[1], acc[1]);
        acc[2] = fmaf(p, w4[2], acc[2]);
        acc[3] = fmaf(p, w4[3], acc[3]);
    }
    *(f32x4*)(partial + ((size_t)kc * 32 + b) * 1024 + t * 4) = acc;
}

// ---------------------------------------------------------------------------
// K5b: final reduce over 16 K-chunks + bias + relu.
// ---------------------------------------------------------------------------
__global__ __launch_bounds__(256) void k_out_final(
    const float* __restrict__ partial, const float* __restrict__ ob,
    float* __restrict__ out)
{
    const int idx = blockIdx.x * 256 + threadIdx.x;
    const int b = idx >> 10, o = idx & 1023;
    float s = ob[o];
#pragma unroll
    for (int kc = 0; kc < 16; ++kc)
        s += partial[((size_t)kc * 32 + b) * 1024 + o];
    out[idx] = fmaxf(s, 0.f);
}

// ---------------------------------------------------------------------------
extern "C" void kernel_launch(void* const* d_in, const int* in_sizes, int n_in,
                              void* d_out, int out_size, void* d_ws, size_t ws_size,
                              hipStream_t stream)
{
    const float* x1     = (const float*)d_in[0];
    const float* x2     = (const float*)d_in[1];
    const int*   x1_len = (const int*)d_in[2];
    const int*   x2_len = (const int*)d_in[3];
    const float* fw     = (const float*)d_in[4];
    const float* fb     = (const float*)d_in[5];
    const float* ow     = (const float*)d_in[6];
    const float* ob     = (const float*)d_in[7];

    float* out  = (float*)d_out;                  // [32, 1024]
    float* attn = out + (size_t)BATCH * 1024;     // [128, 512, 512] f32

    // workspace layout (~275 MB)
    char* wp = (char*)d_ws;
    unsigned short* x1bf   = (unsigned short*)wp; wp += (size_t)BATCH * LL * EE * 2;
    unsigned short* x2bf   = (unsigned short*)wp; wp += (size_t)NB * LL * EE * 2;
    unsigned short* x2t    = (unsigned short*)wp; wp += (size_t)NB * LL * EE * 2;
    unsigned short* Cbuf   = (unsigned short*)wp; wp += (size_t)NB * LL * 1024 * 2;
    unsigned short* fwt    = (unsigned short*)wp; wp += (size_t)EE * 1024 * 2;
    float* pmean   = (float*)wp; wp += (size_t)NB * 4 * EE * 4;
    float* pmax    = (float*)wp; wp += (size_t)NB * 4 * EE * 4;
    float* partial = (float*)wp; wp += (size_t)16 * BATCH * 1024 * 4;

    k_cvt_x1<<<dim3(BATCH * LL * EE / 4 / 256), 256, 0, stream>>>(x1, x1bf);
    k_cvt_x2<<<dim3(8, 8, NB), 256, 0, stream>>>(x2, x2bf, x2t);
    k_cvt_fw<<<dim3(8, 16), 256, 0, stream>>>(fw, fwt);
    k_attn<<<dim3(128, 4), 1024, 0, stream>>>(x1bf, x2bf, x2t, x1_len, x2_len, attn, Cbuf);
    k_fuse_mfma<<<dim3(128, 16), 256, 0, stream>>>(Cbuf, fwt, fb, pmean, pmax);
    k_out_split<<<dim3(16, BATCH), 256, 0, stream>>>(pmean, pmax, ow, partial);
    k_out_final<<<dim3(BATCH * 1024 / 256), 256, 0, stream>>>(partial, ob, out);
}

// Round 4
// 581.235 us; speedup vs baseline: 1.0014x; 1.0014x over previous
//
#include <hip/hip_runtime.h>
#include <cstddef>

// Problem constants (reference: B=32, NDOC=4, L=512, E=512)
#define BATCH 32
#define NB    128
#define LL    512
#define EE    512
#define SCALE 0.044194173824159216f
#define NEG_INF -1e9f

typedef __attribute__((ext_vector_type(4))) float f32x4;
typedef __attribute__((ext_vector_type(8))) short s16x8;          // 8 bf16 (4 VGPRs) MFMA frag
typedef __attribute__((ext_vector_type(4))) unsigned short u16x4;

__device__ __forceinline__ unsigned short f2b(float f) {          // f32 -> bf16 RNE
    unsigned u = __float_as_uint(f);
    u += 0x7FFFu + ((u >> 16) & 1u);
    return (unsigned short)(u >> 16);
}
__device__ __forceinline__ float b2f(unsigned short h) {
    return __uint_as_float(((unsigned)h) << 16);
}

// async global->LDS, 16B per lane. LDS dest = wave-uniform base + lane*16.
__device__ __forceinline__ void gld_lds16(const unsigned short* g, unsigned short* l) {
    __builtin_amdgcn_global_load_lds(
        (const __attribute__((address_space(1))) void*)g,
        (__attribute__((address_space(3))) void*)l, 16, 0, 0);
}

// ---------------------------------------------------------------------------
// Converters: x1 -> bf16; x2 -> bf16 (row) + bf16 transposed; fw -> fw^T bf16
// ---------------------------------------------------------------------------
__global__ __launch_bounds__(256) void k_cvt_x1(
    const float* __restrict__ x1, unsigned short* __restrict__ x1bf)
{
    const size_t idx = (size_t)blockIdx.x * 256 + threadIdx.x;
    f32x4 v = *(const f32x4*)(x1 + idx * 4);
    u16x4 o = { f2b(v[0]), f2b(v[1]), f2b(v[2]), f2b(v[3]) };
    *(u16x4*)(x1bf + idx * 4) = o;
}

__global__ __launch_bounds__(256) void k_cvt_x2(
    const float* __restrict__ x2,
    unsigned short* __restrict__ x2bf, unsigned short* __restrict__ x2t)
{
    __shared__ float T[64][65];
    const int i = blockIdx.z, kb = blockIdx.y * 64, eb = blockIdx.x * 64;
    const float* src = x2 + (size_t)i * LL * EE;
    unsigned short* db = x2bf + (size_t)i * LL * EE;
    unsigned short* dt = x2t  + (size_t)i * LL * EE;
    const int t = threadIdx.x, r16 = t >> 4, c4 = (t & 15) * 4;
#pragma unroll
    for (int p = 0; p < 4; ++p) {
        int row = p * 16 + r16;
        f32x4 v = *(const f32x4*)(src + (size_t)(kb + row) * EE + eb + c4);
        T[row][c4] = v[0]; T[row][c4+1] = v[1]; T[row][c4+2] = v[2]; T[row][c4+3] = v[3];
        u16x4 o = { f2b(v[0]), f2b(v[1]), f2b(v[2]), f2b(v[3]) };
        *(u16x4*)(db + (size_t)(kb + row) * EE + eb + c4) = o;
    }
    __syncthreads();
#pragma unroll
    for (int p = 0; p < 4; ++p) {
        int erow = p * 16 + r16;
        u16x4 o = { f2b(T[c4][erow]), f2b(T[c4+1][erow]),
                    f2b(T[c4+2][erow]), f2b(T[c4+3][erow]) };
        *(u16x4*)(dt + (size_t)(eb + erow) * LL + kb + c4) = o;   // dt[e][k]=src[k][e]
    }
}

// fw [1024][512] -> fwt[e][j'] bf16 with K-interleave j' = (j<512) ? 2j : 2(j-512)+1
// (matches Cbuf's interleaved [diff,prod] pair layout; GEMM result invariant).
__global__ __launch_bounds__(256) void k_cvt_fw(
    const float* __restrict__ fw, unsigned short* __restrict__ fwt)
{
    __shared__ float T[64][65];
    const int jb = blockIdx.y * 64, eb = blockIdx.x * 64;
    const int t = threadIdx.x, r16 = t >> 4, c4 = (t & 15) * 4;
#pragma unroll
    for (int p = 0; p < 4; ++p) {
        int row = p * 16 + r16;
        f32x4 v = *(const f32x4*)(fw + (size_t)(jb + row) * EE + eb + c4);
        T[row][c4] = v[0]; T[row][c4+1] = v[1]; T[row][c4+2] = v[2]; T[row][c4+3] = v[3];
    }
    __syncthreads();
#pragma unroll
    for (int p = 0; p < 4; ++p) {
        int erow = p * 16 + r16;
#pragma unroll
        for (int k = 0; k < 4; ++k) {
            int jold = jb + c4 + k;
            int jn = (jold < 512) ? (2 * jold) : (2 * (jold - 512) + 1);
            fwt[(size_t)(eb + erow) * 1024 + jn] = f2b(T[c4 + k][erow]);
        }
    }
}

// ---------------------------------------------------------------------------
// K1 (fused): scores GEMM -> in-block softmax -> PV GEMM.
// One block = one batch i x 64 q-rows x full k-range (512).
// 80 KB LDS + 512 threads -> 2 blocks/CU: cross-block overlap hides the
// per-barrier vmcnt drains (m114/m97 mechanism) that a 1-block/CU 160KB
// version serialized on.
// LDS map: [0,64K) = scores staging A(4K)+B(32K), then P[64][512] bf16
// swizzled (time-disjoint); [64K,80K) = softmax reduce arrays, then PV
// V-stage [256][32] (time-disjoint).
// ---------------------------------------------------------------------------
__global__ __launch_bounds__(512, 4) void k_attn(
    const unsigned short* __restrict__ x1bf,
    const unsigned short* __restrict__ x2bf,
    const unsigned short* __restrict__ x2t,
    const int* __restrict__ x1_len, const int* __restrict__ x2_len,
    float* __restrict__ attn, unsigned short* __restrict__ Cbuf)
{
    __shared__ __align__(16) char smem[81920];                  // 80 KB
    unsigned short* Ast = (unsigned short*)smem;                // [64][32]  4KB
    unsigned short* Bst = (unsigned short*)(smem + 4096);       // [512][32] 32KB
    // P lives at smem[0..64K), swizzled; addressed via byte offsets.
    unsigned short* Vst = (unsigned short*)(smem + 65536);      // [256][32] 16KB
    float* rowred = (float*)(smem + 65536);                     // [8][64] (aliases Vst)
    float* rowst  = (float*)(smem + 65536 + 2048);              // [64]

    const int i  = blockIdx.x;
    const int q0 = blockIdx.y * 64;
    const unsigned short* Ag = x1bf + (size_t)(i & 31) * LL * EE;
    const unsigned short* Bg = x2bf + (size_t)i * LL * EE;
    const unsigned short* Vg = x2t  + (size_t)i * LL * EE;
    const int t = threadIdx.x, lane = t & 63;
    const int w = t >> 6;                                       // 8 waves
    const int m = lane & 15, quad = lane >> 4;
    const int lrow = lane >> 2, lcol = (lane & 3) * 8;

    f32x4 acc[4][4];                                            // 64 rows x (w-col 64)
#pragma unroll
    for (int r = 0; r < 4; ++r)
#pragma unroll
        for (int c = 0; c < 4; ++c) acc[r][c] = (f32x4){0.f, 0.f, 0.f, 0.f};

    // ---- Phase 1: scores GEMM over e (waves 1x8: same rows, 64-col strips) ----
    for (int e0 = 0; e0 < EE; e0 += 32) {
        if (w < 4)
            gld_lds16(Ag + (size_t)(q0 + w * 16 + lrow) * EE + e0 + lcol, &Ast[w * 512]);
#pragma unroll
        for (int c = 0; c < 4; ++c) {
            const int s = 4 * w + c;                            // B segs 0..31
            gld_lds16(Bg + (size_t)(s * 16 + lrow) * EE + e0 + lcol, &Bst[s * 512]);
        }
        __syncthreads();
        s16x8 af[4], bfr[4];
#pragma unroll
        for (int rt = 0; rt < 4; ++rt)
            af[rt] = *(const s16x8*)&Ast[(rt * 16 + m) * 32 + quad * 8];
#pragma unroll
        for (int ct = 0; ct < 4; ++ct)
            bfr[ct] = *(const s16x8*)&Bst[(w * 64 + ct * 16 + m) * 32 + quad * 8];
#pragma unroll
        for (int rt = 0; rt < 4; ++rt)
#pragma unroll
            for (int ct = 0; ct < 4; ++ct)
                acc[rt][ct] = __builtin_amdgcn_mfma_f32_16x16x32_bf16(
                    af[rt], bfr[ct], acc[rt][ct], 0, 0, 0);
        __syncthreads();
    }

    const int qlen = x1_len[i & 31];
    const int klen = x2_len[i];

    // ---- mask + scale in place ----
#pragma unroll
    for (int rt = 0; rt < 4; ++rt)
#pragma unroll
        for (int reg = 0; reg < 4; ++reg) {
            const int l = q0 + rt * 16 + quad * 4 + reg;
            const bool qok = l < qlen;
#pragma unroll
            for (int ct = 0; ct < 4; ++ct) {
                const int k = w * 64 + ct * 16 + m;
                acc[rt][ct][reg] = (qok && k < klen) ? acc[rt][ct][reg] * SCALE : NEG_INF;
            }
        }

    // ---- row max: per-wave 64-col partial -> LDS -> 8-way reduce ----
#pragma unroll
    for (int rt = 0; rt < 4; ++rt)
#pragma unroll
        for (int reg = 0; reg < 4; ++reg) {
            float v = fmaxf(fmaxf(acc[rt][0][reg], acc[rt][1][reg]),
                            fmaxf(acc[rt][2][reg], acc[rt][3][reg]));
            v = fmaxf(v, __shfl_xor(v, 1));
            v = fmaxf(v, __shfl_xor(v, 2));
            v = fmaxf(v, __shfl_xor(v, 4));
            v = fmaxf(v, __shfl_xor(v, 8));
            if (m == 0)
                rowred[w * 64 + rt * 16 + quad * 4 + reg] = v;
        }
    __syncthreads();
    if (t < 64) {
        float mx = rowred[t];
#pragma unroll
        for (int c = 1; c < 8; ++c) mx = fmaxf(mx, rowred[c * 64 + t]);
        rowst[t] = mx;
    }
    __syncthreads();

    // ---- exp + row sum ----
#pragma unroll
    for (int rt = 0; rt < 4; ++rt)
#pragma unroll
        for (int reg = 0; reg < 4; ++reg) {
            const int lloc = rt * 16 + quad * 4 + reg;
            const float mx = rowst[lloc];
            float s = 0.f;
#pragma unroll
            for (int ct = 0; ct < 4; ++ct) {
                float p = __expf(acc[rt][ct][reg] - mx);
                acc[rt][ct][reg] = p;
                s += p;
            }
            s += __shfl_xor(s, 1);
            s += __shfl_xor(s, 2);
            s += __shfl_xor(s, 4);
            s += __shfl_xor(s, 8);
            if (m == 0) rowred[w * 64 + lloc] = s;
        }
    __syncthreads();
    if (t < 64) {
        float s = 0.f;
#pragma unroll
        for (int c = 0; c < 8; ++c) s += rowred[c * 64 + t];
        rowst[t] = 1.0f / s;
    }
    __syncthreads();

    // ---- normalize: write attn f32 (output) + P bf16 (LDS, swizzled) ----
    float* op = attn + (size_t)i * LL * LL;
#pragma unroll
    for (int rt = 0; rt < 4; ++rt)
#pragma unroll
        for (int reg = 0; reg < 4; ++reg) {
            const int lloc = rt * 16 + quad * 4 + reg;
            const float inv = rowst[lloc];
#pragma unroll
            for (int ct = 0; ct < 4; ++ct) {
                const int k = w * 64 + ct * 16 + m;
                float p = acc[rt][ct][reg] * inv;
                op[(size_t)(q0 + lloc) * LL + k] = p;
                unsigned off = (unsigned)(lloc * 1024 + k * 2) ^ (unsigned)((lloc & 7) << 4);
                *(unsigned short*)(smem + off) = f2b(p);
            }
        }
    __syncthreads();                                           // P complete; rowst dead

    // ---- Phase 2: PV GEMM, two e-halves of 256 (waves 2x4) ----
    const int pwr = w >> 2, pwc = w & 3;
    unsigned short* Cb = Cbuf + (size_t)i * LL * 1024;
#pragma unroll
    for (int eh = 0; eh < 2; ++eh) {
        f32x4 acc2[2][4];
#pragma unroll
        for (int r = 0; r < 2; ++r)
#pragma unroll
            for (int c = 0; c < 4; ++c) acc2[r][c] = (f32x4){0.f, 0.f, 0.f, 0.f};

        for (int kt = 0; kt < 16; ++kt) {
            const int k0 = kt * 32;
#pragma unroll
            for (int c = 0; c < 2; ++c) {
                const int s = 2 * w + c;                        // V segs 0..15
                gld_lds16(Vg + (size_t)(eh * 256 + s * 16 + lrow) * LL + k0 + lcol,
                          &Vst[s * 512]);
            }
            __syncthreads();
            s16x8 paf[2], pbf[4];
#pragma unroll
            for (int rt = 0; rt < 2; ++rt) {
                const int lr = pwr * 32 + rt * 16 + m;
                unsigned off = (unsigned)(lr * 1024 + (k0 + quad * 8) * 2)
                               ^ (unsigned)((lr & 7) << 4);
                paf[rt] = *(const s16x8*)(smem + off);
            }
#pragma unroll
            for (int ct = 0; ct < 4; ++ct)
                pbf[ct] = *(const s16x8*)&Vst[(pwc * 64 + ct * 16 + m) * 32 + quad * 8];
#pragma unroll
            for (int rt = 0; rt < 2; ++rt)
#pragma unroll
                for (int ct = 0; ct < 4; ++ct)
                    acc2[rt][ct] = __builtin_amdgcn_mfma_f32_16x16x32_bf16(
                        paf[rt], pbf[ct], acc2[rt][ct], 0, 0, 0);
            __syncthreads();
        }

        // epilogue: Cbuf[l][2e]=x1-att, [2e+1]=x1*att
#pragma unroll
        for (int rt = 0; rt < 2; ++rt)
#pragma unroll
            for (int reg = 0; reg < 4; ++reg) {
                const int l = q0 + pwr * 32 + rt * 16 + quad * 4 + reg;
#pragma unroll
                for (int ct = 0; ct < 4; ++ct) {
                    const int e = eh * 256 + pwc * 64 + ct * 16 + m;
                    float att = acc2[rt][ct][reg];
                    float xv  = b2f(Ag[(size_t)l * EE + e]);
                    unsigned pr = (unsigned)f2b(xv - att) | ((unsigned)f2b(xv * att) << 16);
                    *(unsigned*)(Cb + (size_t)l * 1024 + 2 * e) = pr;
                }
            }
    }
}

// ---------------------------------------------------------------------------
// K4: fus = relu(Cbuf @ fw + b) with per-l-tile mean/max pooling partials.
// R2 form: single-buffer 2-barrier, 34KB LDS -> 4 blocks/CU.
// ---------------------------------------------------------------------------
__global__ __launch_bounds__(256) void k_fuse_mfma(
    const unsigned short* __restrict__ Cbuf,
    const unsigned short* __restrict__ fwt,
    const float* __restrict__ fb,
    float* __restrict__ pmean, float* __restrict__ pmax)
{
    __shared__ unsigned short Al[128 * 32];
    __shared__ unsigned short Bl[128 * 32];
    __shared__ float psum[2][128];
    __shared__ float pmx[2][128];
    const int i  = blockIdx.x;
    const int lt = blockIdx.y >> 2;
    const int e0 = (blockIdx.y & 3) * 128;
    const unsigned short* Ab = Cbuf + ((size_t)i * LL + lt * 128) * 1024;
    const int t = threadIdx.x, lane = t & 63;
    const int w = t >> 6, wrow = w >> 1, wcol = w & 1;
    const int m = lane & 15, quad = lane >> 4;
    const int lrow = lane >> 2, lcol = (lane & 3) * 8;

    float bias[4];
#pragma unroll
    for (int ct = 0; ct < 4; ++ct) bias[ct] = fb[e0 + wcol * 64 + ct * 16 + m];
    float csum[4] = {0.f, 0.f, 0.f, 0.f};
    float cmax[4] = {-3e38f, -3e38f, -3e38f, -3e38f};

    f32x4 acc[4][4];
#pragma unroll
    for (int r = 0; r < 4; ++r)
#pragma unroll
        for (int c = 0; c < 4; ++c) acc[r][c] = (f32x4){0.f, 0.f, 0.f, 0.f};

    for (int j0 = 0; j0 < 1024; j0 += 32) {
#pragma unroll
        for (int c = 0; c < 2; ++c) {
            const int s = c * 4 + w;
            gld_lds16(Ab + (size_t)(s * 16 + lrow) * 1024 + j0 + lcol, &Al[s * 512]);
            gld_lds16(fwt + (size_t)(e0 + s * 16 + lrow) * 1024 + j0 + lcol, &Bl[s * 512]);
        }
        __syncthreads();
        s16x8 af[4], bfr[4];
#pragma unroll
        for (int rt = 0; rt < 4; ++rt)
            af[rt] = *(const s16x8*)&Al[(wrow * 64 + rt * 16 + m) * 32 + quad * 8];
#pragma unroll
        for (int ct = 0; ct < 4; ++ct)
            bfr[ct] = *(const s16x8*)&Bl[(wcol * 64 + ct * 16 + m) * 32 + quad * 8];
#pragma unroll
        for (int rt = 0; rt < 4; ++rt)
#pragma unroll
            for (int ct = 0; ct < 4; ++ct)
                acc[rt][ct] = __builtin_amdgcn_mfma_f32_16x16x32_bf16(
                    af[rt], bfr[ct], acc[rt][ct], 0, 0, 0);
        __syncthreads();
    }
#pragma unroll
    for (int rt = 0; rt < 4; ++rt)
#pragma unroll
        for (int reg = 0; reg < 4; ++reg)
#pragma unroll
            for (int ct = 0; ct < 4; ++ct) {
                float f = fmaxf(acc[rt][ct][reg] + bias[ct], 0.f);
                csum[ct] += f;
                cmax[ct] = fmaxf(cmax[ct], f);
            }
#pragma unroll
    for (int ct = 0; ct < 4; ++ct) {
        csum[ct] += __shfl_xor(csum[ct], 16);
        csum[ct] += __shfl_xor(csum[ct], 32);
        cmax[ct] = fmaxf(cmax[ct], __shfl_xor(cmax[ct], 16));
        cmax[ct] = fmaxf(cmax[ct], __shfl_xor(cmax[ct], 32));
    }
    if (quad == 0) {
#pragma unroll
        for (int ct = 0; ct < 4; ++ct) {
            psum[wrow][wcol * 64 + ct * 16 + m] = csum[ct];
            pmx[wrow][wcol * 64 + ct * 16 + m] = cmax[ct];
        }
    }
    __syncthreads();
    if (t < 128) {
        float s  = psum[0][t] + psum[1][t];
        float mx = fmaxf(pmx[0][t], pmx[1][t]);
        pmean[((size_t)i * 4 + lt) * EE + e0 + t] = s;     // raw sum over 128 l's
        pmax[((size_t)i * 4 + lt) * EE + e0 + t]  = mx;
    }
}

// ---------------------------------------------------------------------------
// K5a: split-K partial GEMM for the output head; reduces the 4 l-tile pooling
// partials inline while loading the pooled vector.
// ---------------------------------------------------------------------------
__global__ __launch_bounds__(256) void k_out_split(
    const float* __restrict__ pmean, const float* __restrict__ pmax,
    const float* __restrict__ ow, float* __restrict__ partial)
{
    __shared__ float ps[256];
    const int kc = blockIdx.x;
    const int b  = blockIdx.y;
    const int t  = threadIdx.x;
    const int j  = kc * 256 + t;
    const int jj = (j < 2048) ? j : j - 2048;
    const int ii = 4 * b + (jj >> 9);
    const int e  = jj & 511;
    float v;
    if (j < 2048) {
        const float* bp = pmean + (size_t)ii * 4 * EE + e;
        v = (bp[0] + bp[512] + bp[1024] + bp[1536]) * (1.0f / 512.0f);
    } else {
        const float* bp = pmax + (size_t)ii * 4 * EE + e;
        v = fmaxf(fmaxf(bp[0], bp[512]), fmaxf(bp[1024], bp[1536]));
    }
    ps[t] = v;
    __syncthreads();
    f32x4 acc = {0.f, 0.f, 0.f, 0.f};
    const float* wp = ow + (size_t)kc * 256 * 1024 + t * 4;
#pragma unroll 8
    for (int q = 0; q < 256; ++q) {
        f32x4 w4 = *(const f32x4*)(wp + (size_t)q * 1024);
        float p = ps[q];
        acc[0] = fmaf(p, w4[0], acc[0]);
        acc[1] = fmaf(p, w4[1], acc[1]);
        acc[2] = fmaf(p, w4[2], acc[2]);
        acc[3] = fmaf(p, w4[3], acc[3]);
    }
    *(f32x4*)(partial + ((size_t)kc * 32 + b) * 1024 + t * 4) = acc;
}

// ---------------------------------------------------------------------------
// K5b: final reduce over 16 K-chunks + bias + relu.
// ---------------------------------------------------------------------------
__global__ __launch_bounds__(256) void k_out_final(
    const float* __restrict__ partial, const float* __restrict__ ob,
    float* __restrict__ out)
{
    const int idx = blockIdx.x * 256 + threadIdx.x;
    const int b = idx >> 10, o = idx & 1023;
    float s = ob[o];
#pragma unroll
    for (int kc = 0; kc < 16; ++kc)
        s += partial[((size_t)kc * 32 + b) * 1024 + o];
    out[idx] = fmaxf(s, 0.f);
}

// ---------------------------------------------------------------------------
extern "C" void kernel_launch(void* const* d_in, const int* in_sizes, int n_in,
                              void* d_out, int out_size, void* d_ws, size_t ws_size,
                              hipStream_t stream)
{
    const float* x1     = (const float*)d_in[0];
    const float* x2     = (const float*)d_in[1];
    const int*   x1_len = (const int*)d_in[2];
    const int*   x2_len = (const int*)d_in[3];
    const float* fw     = (const float*)d_in[4];
    const float* fb     = (const float*)d_in[5];
    const float* ow     = (const float*)d_in[6];
    const float* ob     = (const float*)d_in[7];

    float* out  = (float*)d_out;                  // [32, 1024]
    float* attn = out + (size_t)BATCH * 1024;     // [128, 512, 512] f32

    // workspace layout (~275 MB)
    char* wp = (char*)d_ws;
    unsigned short* x1bf   = (unsigned short*)wp; wp += (size_t)BATCH * LL * EE * 2;
    unsigned short* x2bf   = (unsigned short*)wp; wp += (size_t)NB * LL * EE * 2;
    unsigned short* x2t    = (unsigned short*)wp; wp += (size_t)NB * LL * EE * 2;
    unsigned short* Cbuf   = (unsigned short*)wp; wp += (size_t)NB * LL * 1024 * 2;
    unsigned short* fwt    = (unsigned short*)wp; wp += (size_t)EE * 1024 * 2;
    float* pmean   = (float*)wp; wp += (size_t)NB * 4 * EE * 4;
    float* pmax    = (float*)wp; wp += (size_t)NB * 4 * EE * 4;
    float* partial = (float*)wp; wp += (size_t)16 * BATCH * 1024 * 4;

    k_cvt_x1<<<dim3(BATCH * LL * EE / 4 / 256), 256, 0, stream>>>(x1, x1bf);
    k_cvt_x2<<<dim3(8, 8, NB), 256, 0, stream>>>(x2, x2bf, x2t);
    k_cvt_fw<<<dim3(8, 16), 256, 0, stream>>>(fw, fwt);
    k_attn<<<dim3(128, 8), 512, 0, stream>>>(x1bf, x2bf, x2t, x1_len, x2_len, attn, Cbuf);
    k_fuse_mfma<<<dim3(128, 16), 256, 0, stream>>>(Cbuf, fwt, fb, pmean, pmax);
    k_out_split<<<dim3(16, BATCH), 256, 0, stream>>>(pmean, pmax, ow, partial);
    k_out_final<<<dim3(BATCH * 1024 / 256), 256, 0, stream>>>(partial, ob, out);
}

// Round 5
// 576.733 us; speedup vs baseline: 1.0092x; 1.0078x over previous
//
#include <hip/hip_runtime.h>
#include <cstddef>

// Problem constants (reference: B=32, NDOC=4, L=512, E=512)
#define BATCH 32
#define NB    128
#define LL    512
#define EE    512
#define SCALE 0.044194173824159216f
#define NEG_INF -1e9f

typedef __attribute__((ext_vector_type(4))) float f32x4;
typedef __attribute__((ext_vector_type(8))) short s16x8;          // 8 bf16 (4 VGPRs) MFMA frag
typedef __attribute__((ext_vector_type(4))) unsigned short u16x4;

// counted end-of-step fence: my stage landed + my LDS reads done, then barrier.
// (all waves passing it => whole next buffer valid, current buffer reads done)
#define STEP_FENCE() asm volatile("s_waitcnt vmcnt(0) lgkmcnt(0)\n\ts_barrier" ::: "memory")

__device__ __forceinline__ unsigned short f2b(float f) {          // f32 -> bf16 RNE
    unsigned u = __float_as_uint(f);
    u += 0x7FFFu + ((u >> 16) & 1u);
    return (unsigned short)(u >> 16);
}
__device__ __forceinline__ float b2f(unsigned short h) {
    return __uint_as_float(((unsigned)h) << 16);
}

// async global->LDS, 16B per lane. LDS dest = wave-uniform base + lane*16.
__device__ __forceinline__ void gld_lds16(const unsigned short* g, unsigned short* l) {
    __builtin_amdgcn_global_load_lds(
        (const __attribute__((address_space(1))) void*)g,
        (__attribute__((address_space(3))) void*)l, 16, 0, 0);
}

// ---------------------------------------------------------------------------
// Converters: x1 -> bf16; x2 -> bf16 (row) + bf16 transposed; fw -> fw^T bf16
// ---------------------------------------------------------------------------
__global__ __launch_bounds__(256) void k_cvt_x1(
    const float* __restrict__ x1, unsigned short* __restrict__ x1bf)
{
    const size_t idx = (size_t)blockIdx.x * 256 + threadIdx.x;
    f32x4 v = *(const f32x4*)(x1 + idx * 4);
    u16x4 o = { f2b(v[0]), f2b(v[1]), f2b(v[2]), f2b(v[3]) };
    *(u16x4*)(x1bf + idx * 4) = o;
}

__global__ __launch_bounds__(256) void k_cvt_x2(
    const float* __restrict__ x2,
    unsigned short* __restrict__ x2bf, unsigned short* __restrict__ x2t)
{
    __shared__ float T[64][65];
    const int i = blockIdx.z, kb = blockIdx.y * 64, eb = blockIdx.x * 64;
    const float* src = x2 + (size_t)i * LL * EE;
    unsigned short* db = x2bf + (size_t)i * LL * EE;
    unsigned short* dt = x2t  + (size_t)i * LL * EE;
    const int t = threadIdx.x, r16 = t >> 4, c4 = (t & 15) * 4;
#pragma unroll
    for (int p = 0; p < 4; ++p) {
        int row = p * 16 + r16;
        f32x4 v = *(const f32x4*)(src + (size_t)(kb + row) * EE + eb + c4);
        T[row][c4] = v[0]; T[row][c4+1] = v[1]; T[row][c4+2] = v[2]; T[row][c4+3] = v[3];
        u16x4 o = { f2b(v[0]), f2b(v[1]), f2b(v[2]), f2b(v[3]) };
        *(u16x4*)(db + (size_t)(kb + row) * EE + eb + c4) = o;
    }
    __syncthreads();
#pragma unroll
    for (int p = 0; p < 4; ++p) {
        int erow = p * 16 + r16;
        u16x4 o = { f2b(T[c4][erow]), f2b(T[c4+1][erow]),
                    f2b(T[c4+2][erow]), f2b(T[c4+3][erow]) };
        *(u16x4*)(dt + (size_t)(eb + erow) * LL + kb + c4) = o;   // dt[e][k]=src[k][e]
    }
}

// fw [1024][512] -> fwt[e][j'] bf16 with K-interleave j' = (j<512) ? 2j : 2(j-512)+1
// (matches Cbuf's interleaved [diff,prod] pair layout; GEMM result invariant).
__global__ __launch_bounds__(256) void k_cvt_fw(
    const float* __restrict__ fw, unsigned short* __restrict__ fwt)
{
    __shared__ float T[64][65];
    const int jb = blockIdx.y * 64, eb = blockIdx.x * 64;
    const int t = threadIdx.x, r16 = t >> 4, c4 = (t & 15) * 4;
#pragma unroll
    for (int p = 0; p < 4; ++p) {
        int row = p * 16 + r16;
        f32x4 v = *(const f32x4*)(fw + (size_t)(jb + row) * EE + eb + c4);
        T[row][c4] = v[0]; T[row][c4+1] = v[1]; T[row][c4+2] = v[2]; T[row][c4+3] = v[3];
    }
    __syncthreads();
#pragma unroll
    for (int p = 0; p < 4; ++p) {
        int erow = p * 16 + r16;
#pragma unroll
        for (int k = 0; k < 4; ++k) {
            int jold = jb + c4 + k;
            int jn = (jold < 512) ? (2 * jold) : (2 * (jold - 512) + 1);
            fwt[(size_t)(eb + erow) * 1024 + jn] = f2b(T[c4 + k][erow]);
        }
    }
}

// ---------------------------------------------------------------------------
// K1 (fused): scores GEMM -> in-block softmax -> PV GEMM.
// One block = one batch i x 128 q-rows x full k-range (512). 1024 thr, 160KB.
// T3-minimum counted schedule (m248v2): per K-step {stage NEXT slice into
// other dbuf; ds_read+MFMA current; s_waitcnt vmcnt(0) lgkmcnt(0); s_barrier}.
// Stage latency is covered by the step's own compute; one barrier/step.
// XCD remap: flat=x+y*128 (512 blocks); xcd=flat&7; i=xcd*16+(idx>>2);
// qt=idx&3 -> each XCD runs 16 consecutive i's, 4 q-tiles adjacent in time
// (concurrent L2 working set ~halved vs naive mapping).
// LDS 160KB: [0,80K) scores dbuf A0|A1|B0|B1, then P[128][512] swizzled at
// [0,128K); [128K,160K) softmax reduce arrays, then PV V-dbuf. Time-disjoint.
// ---------------------------------------------------------------------------
__global__ __launch_bounds__(1024, 4) void k_attn(
    const unsigned short* __restrict__ x1bf,
    const unsigned short* __restrict__ x2bf,
    const unsigned short* __restrict__ x2t,
    const int* __restrict__ x1_len, const int* __restrict__ x2_len,
    float* __restrict__ attn, unsigned short* __restrict__ Cbuf)
{
    __shared__ __align__(16) char smem[163840];                 // 160 KB
    unsigned short* Ast0 = (unsigned short*)smem;               // [128][32]  8KB
    unsigned short* Ast1 = (unsigned short*)(smem + 8192);      // 8KB
    unsigned short* Bst0 = (unsigned short*)(smem + 16384);     // [512][32] 32KB
    unsigned short* Bst1 = (unsigned short*)(smem + 49152);     // 32KB -> 80KB
    // P lives at smem[0..128K), swizzled; addressed via byte offsets.
    float* rowred = (float*)(smem + 131072);                    // [8][128] 4KB
    float* rowst  = (float*)(smem + 131072 + 4096);             // [128]
    unsigned short* Vst0 = (unsigned short*)(smem + 131072);    // [256][32] 16KB
    unsigned short* Vst1 = (unsigned short*)(smem + 147456);    // 16KB

    const int flat = blockIdx.x + blockIdx.y * 128;             // [0,512)
    const int xcd  = flat & 7;
    const int idx  = flat >> 3;                                 // [0,64)
    const int i    = xcd * 16 + (idx >> 2);
    const int q0   = (idx & 3) * 128;
    const unsigned short* Ag = x1bf + (size_t)(i & 31) * LL * EE;
    const unsigned short* Bg = x2bf + (size_t)i * LL * EE;
    const unsigned short* Vg = x2t  + (size_t)i * LL * EE;
    const int t = threadIdx.x, lane = t & 63;
    const int w = t >> 6;                                       // 16 waves
    const int m = lane & 15, quad = lane >> 4;
    const int lrow = lane >> 2, lcol = (lane & 3) * 8;
    const int wrow = w >> 3, wcol = w & 7;                      // scores: 2x8 waves

    f32x4 acc[4][4];
#pragma unroll
    for (int r = 0; r < 4; ++r)
#pragma unroll
        for (int c = 0; c < 4; ++c) acc[r][c] = (f32x4){0.f, 0.f, 0.f, 0.f};

    // ---- Phase 1: scores GEMM over e (counted single-barrier schedule) ----
    // prologue: stage slice 0 into buf0
    if (w < 8)
        gld_lds16(Ag + (size_t)(q0 + w * 16 + lrow) * EE + lcol, &Ast0[w * 512]);
    gld_lds16(Bg + (size_t)((2 * w) * 16 + lrow) * EE + lcol, &Bst0[(2 * w) * 512]);
    gld_lds16(Bg + (size_t)((2 * w + 1) * 16 + lrow) * EE + lcol, &Bst0[(2 * w + 1) * 512]);
    STEP_FENCE();

    for (int it = 0; it < 16; ++it) {
        unsigned short* Ac = (it & 1) ? Ast1 : Ast0;
        unsigned short* Bc = (it & 1) ? Bst1 : Bst0;
        if (it < 15) {                                          // stage NEXT first
            unsigned short* An = (it & 1) ? Ast0 : Ast1;
            unsigned short* Bn = (it & 1) ? Bst0 : Bst1;
            const int e0n = (it + 1) * 32;
            if (w < 8)
                gld_lds16(Ag + (size_t)(q0 + w * 16 + lrow) * EE + e0n + lcol, &An[w * 512]);
            gld_lds16(Bg + (size_t)((2 * w) * 16 + lrow) * EE + e0n + lcol, &Bn[(2 * w) * 512]);
            gld_lds16(Bg + (size_t)((2 * w + 1) * 16 + lrow) * EE + e0n + lcol, &Bn[(2 * w + 1) * 512]);
        }
        s16x8 af[4], bfr[4];
#pragma unroll
        for (int rt = 0; rt < 4; ++rt)
            af[rt] = *(const s16x8*)&Ac[(wrow * 64 + rt * 16 + m) * 32 + quad * 8];
#pragma unroll
        for (int ct = 0; ct < 4; ++ct)
            bfr[ct] = *(const s16x8*)&Bc[(wcol * 64 + ct * 16 + m) * 32 + quad * 8];
#pragma unroll
        for (int rt = 0; rt < 4; ++rt)
#pragma unroll
            for (int ct = 0; ct < 4; ++ct)
                acc[rt][ct] = __builtin_amdgcn_mfma_f32_16x16x32_bf16(
                    af[rt], bfr[ct], acc[rt][ct], 0, 0, 0);
        STEP_FENCE();                                           // stage landed, reads done
    }

    const int qlen = x1_len[i & 31];
    const int klen = x2_len[i];

    // ---- mask + scale in place ----
#pragma unroll
    for (int rt = 0; rt < 4; ++rt)
#pragma unroll
        for (int reg = 0; reg < 4; ++reg) {
            const int l = q0 + wrow * 64 + rt * 16 + quad * 4 + reg;
            const bool qok = l < qlen;
#pragma unroll
            for (int ct = 0; ct < 4; ++ct) {
                const int k = wcol * 64 + ct * 16 + m;
                acc[rt][ct][reg] = (qok && k < klen) ? acc[rt][ct][reg] * SCALE : NEG_INF;
            }
        }

    // ---- row max: per-wave 64-col partial -> LDS -> 8-way reduce ----
#pragma unroll
    for (int rt = 0; rt < 4; ++rt)
#pragma unroll
        for (int reg = 0; reg < 4; ++reg) {
            float v = fmaxf(fmaxf(acc[rt][0][reg], acc[rt][1][reg]),
                            fmaxf(acc[rt][2][reg], acc[rt][3][reg]));
            v = fmaxf(v, __shfl_xor(v, 1));
            v = fmaxf(v, __shfl_xor(v, 2));
            v = fmaxf(v, __shfl_xor(v, 4));
            v = fmaxf(v, __shfl_xor(v, 8));
            if (m == 0)
                rowred[wcol * 128 + wrow * 64 + rt * 16 + quad * 4 + reg] = v;
        }
    __syncthreads();
    if (t < 128) {
        float mx = rowred[t];
#pragma unroll
        for (int c = 1; c < 8; ++c) mx = fmaxf(mx, rowred[c * 128 + t]);
        rowst[t] = mx;
    }
    __syncthreads();

    // ---- exp + row sum ----
#pragma unroll
    for (int rt = 0; rt < 4; ++rt)
#pragma unroll
        for (int reg = 0; reg < 4; ++reg) {
            const int lloc = wrow * 64 + rt * 16 + quad * 4 + reg;
            const float mx = rowst[lloc];
            float s = 0.f;
#pragma unroll
            for (int ct = 0; ct < 4; ++ct) {
                float p = __expf(acc[rt][ct][reg] - mx);
                acc[rt][ct][reg] = p;
                s += p;
            }
            s += __shfl_xor(s, 1);
            s += __shfl_xor(s, 2);
            s += __shfl_xor(s, 4);
            s += __shfl_xor(s, 8);
            if (m == 0) rowred[wcol * 128 + lloc] = s;
        }
    __syncthreads();
    if (t < 128) {
        float s = 0.f;
#pragma unroll
        for (int c = 0; c < 8; ++c) s += rowred[c * 128 + t];
        rowst[t] = 1.0f / s;
    }
    __syncthreads();

    // ---- normalize: write attn f32 (output) + P bf16 (LDS, swizzled) ----
    float* op = attn + (size_t)i * LL * LL;
#pragma unroll
    for (int rt = 0; rt < 4; ++rt)
#pragma unroll
        for (int reg = 0; reg < 4; ++reg) {
            const int lloc = wrow * 64 + rt * 16 + quad * 4 + reg;
            const float inv = rowst[lloc];
#pragma unroll
            for (int ct = 0; ct < 4; ++ct) {
                const int k = wcol * 64 + ct * 16 + m;
                float p = acc[rt][ct][reg] * inv;
                op[(size_t)(q0 + lloc) * LL + k] = p;
                unsigned off = (unsigned)(lloc * 1024 + k * 2) ^ (unsigned)((lloc & 7) << 4);
                *(unsigned short*)(smem + off) = f2b(p);
            }
        }
    __syncthreads();                                           // P complete; rowst dead

    // ---- Phase 2: PV GEMM, two e-halves of 256 (waves 4x4, counted sched) ----
    const int pwr = w >> 2, pwc = w & 3;
    unsigned short* Cb = Cbuf + (size_t)i * LL * 1024;
#pragma unroll
    for (int eh = 0; eh < 2; ++eh) {
        f32x4 acc2[2][4];
#pragma unroll
        for (int r = 0; r < 2; ++r)
#pragma unroll
            for (int c = 0; c < 4; ++c) acc2[r][c] = (f32x4){0.f, 0.f, 0.f, 0.f};

        // prologue: stage kt=0 into V0 (1 load/thread: 16 wave-segs of 16 rows)
        gld_lds16(Vg + (size_t)(eh * 256 + w * 16 + lrow) * LL + lcol, &Vst0[w * 512]);
        STEP_FENCE();

        for (int kt = 0; kt < 16; ++kt) {
            const int k0 = kt * 32;
            unsigned short* Vc = (kt & 1) ? Vst1 : Vst0;
            if (kt < 15) {
                unsigned short* Vn = (kt & 1) ? Vst0 : Vst1;
                gld_lds16(Vg + (size_t)(eh * 256 + w * 16 + lrow) * LL + k0 + 32 + lcol,
                          &Vn[w * 512]);
            }
            s16x8 paf[2], pbf[4];
#pragma unroll
            for (int rt = 0; rt < 2; ++rt) {
                const int lr = pwr * 32 + rt * 16 + m;
                unsigned off = (unsigned)(lr * 1024 + (k0 + quad * 8) * 2)
                               ^ (unsigned)((lr & 7) << 4);
                paf[rt] = *(const s16x8*)(smem + off);
            }
#pragma unroll
            for (int ct = 0; ct < 4; ++ct)
                pbf[ct] = *(const s16x8*)&Vc[(pwc * 64 + ct * 16 + m) * 32 + quad * 8];
#pragma unroll
            for (int rt = 0; rt < 2; ++rt)
#pragma unroll
                for (int ct = 0; ct < 4; ++ct)
                    acc2[rt][ct] = __builtin_amdgcn_mfma_f32_16x16x32_bf16(
                        paf[rt], pbf[ct], acc2[rt][ct], 0, 0, 0);
            STEP_FENCE();
        }

        // epilogue: Cbuf[l][2e]=x1-att, [2e+1]=x1*att
#pragma unroll
        for (int rt = 0; rt < 2; ++rt)
#pragma unroll
            for (int reg = 0; reg < 4; ++reg) {
                const int l = q0 + pwr * 32 + rt * 16 + quad * 4 + reg;
#pragma unroll
                for (int ct = 0; ct < 4; ++ct) {
                    const int e = eh * 256 + pwc * 64 + ct * 16 + m;
                    float att = acc2[rt][ct][reg];
                    float xv  = b2f(Ag[(size_t)l * EE + e]);
                    unsigned pr = (unsigned)f2b(xv - att) | ((unsigned)f2b(xv * att) << 16);
                    *(unsigned*)(Cb + (size_t)l * 1024 + 2 * e) = pr;
                }
            }
    }
}

// ---------------------------------------------------------------------------
// K4: fus = relu(Cbuf @ fw + b) with per-l-tile mean/max pooling partials.
// R2 form: single-buffer 2-barrier, 34KB LDS -> 4 blocks/CU.
// ---------------------------------------------------------------------------
__global__ __launch_bounds__(256) void k_fuse_mfma(
    const unsigned short* __restrict__ Cbuf,
    const unsigned short* __restrict__ fwt,
    const float* __restrict__ fb,
    float* __restrict__ pmean, float* __restrict__ pmax)
{
    __shared__ unsigned short Al[128 * 32];
    __shared__ unsigned short Bl[128 * 32];
    __shared__ float psum[2][128];
    __shared__ float pmx[2][128];
    const int i  = blockIdx.x;
    const int lt = blockIdx.y >> 2;
    const int e0 = (blockIdx.y & 3) * 128;
    const unsigned short* Ab = Cbuf + ((size_t)i * LL + lt * 128) * 1024;
    const int t = threadIdx.x, lane = t & 63;
    const int w = t >> 6, wrow = w >> 1, wcol = w & 1;
    const int m = lane & 15, quad = lane >> 4;
    const int lrow = lane >> 2, lcol = (lane & 3) * 8;

    float bias[4];
#pragma unroll
    for (int ct = 0; ct < 4; ++ct) bias[ct] = fb[e0 + wcol * 64 + ct * 16 + m];
    float csum[4] = {0.f, 0.f, 0.f, 0.f};
    float cmax[4] = {-3e38f, -3e38f, -3e38f, -3e38f};

    f32x4 acc[4][4];
#pragma unroll
    for (int r = 0; r < 4; ++r)
#pragma unroll
        for (int c = 0; c < 4; ++c) acc[r][c] = (f32x4){0.f, 0.f, 0.f, 0.f};

    for (int j0 = 0; j0 < 1024; j0 += 32) {
#pragma unroll
        for (int c = 0; c < 2; ++c) {
            const int s = c * 4 + w;
            gld_lds16(Ab + (size_t)(s * 16 + lrow) * 1024 + j0 + lcol, &Al[s * 512]);
            gld_lds16(fwt + (size_t)(e0 + s * 16 + lrow) * 1024 + j0 + lcol, &Bl[s * 512]);
        }
        __syncthreads();
        s16x8 af[4], bfr[4];
#pragma unroll
        for (int rt = 0; rt < 4; ++rt)
            af[rt] = *(const s16x8*)&Al[(wrow * 64 + rt * 16 + m) * 32 + quad * 8];
#pragma unroll
        for (int ct = 0; ct < 4; ++ct)
            bfr[ct] = *(const s16x8*)&Bl[(wcol * 64 + ct * 16 + m) * 32 + quad * 8];
#pragma unroll
        for (int rt = 0; rt < 4; ++rt)
#pragma unroll
            for (int ct = 0; ct < 4; ++ct)
                acc[rt][ct] = __builtin_amdgcn_mfma_f32_16x16x32_bf16(
                    af[rt], bfr[ct], acc[rt][ct], 0, 0, 0);
        __syncthreads();
    }
#pragma unroll
    for (int rt = 0; rt < 4; ++rt)
#pragma unroll
        for (int reg = 0; reg < 4; ++reg)
#pragma unroll
            for (int ct = 0; ct < 4; ++ct) {
                float f = fmaxf(acc[rt][ct][reg] + bias[ct], 0.f);
                csum[ct] += f;
                cmax[ct] = fmaxf(cmax[ct], f);
            }
#pragma unroll
    for (int ct = 0; ct < 4; ++ct) {
        csum[ct] += __shfl_xor(csum[ct], 16);
        csum[ct] += __shfl_xor(csum[ct], 32);
        cmax[ct] = fmaxf(cmax[ct], __shfl_xor(cmax[ct], 16));
        cmax[ct] = fmaxf(cmax[ct], __shfl_xor(cmax[ct], 32));
    }
    if (quad == 0) {
#pragma unroll
        for (int ct = 0; ct < 4; ++ct) {
            psum[wrow][wcol * 64 + ct * 16 + m] = csum[ct];
            pmx[wrow][wcol * 64 + ct * 16 + m] = cmax[ct];
        }
    }
    __syncthreads();
    if (t < 128) {
        float s  = psum[0][t] + psum[1][t];
        float mx = fmaxf(pmx[0][t], pmx[1][t]);
        pmean[((size_t)i * 4 + lt) * EE + e0 + t] = s;     // raw sum over 128 l's
        pmax[((size_t)i * 4 + lt) * EE + e0 + t]  = mx;
    }
}

// ---------------------------------------------------------------------------
// K5a: split-K partial GEMM for the output head; reduces the 4 l-tile pooling
// partials inline while loading the pooled vector.
// ---------------------------------------------------------------------------
__global__ __launch_bounds__(256) void k_out_split(
    const float* __restrict__ pmean, const float* __restrict__ pmax,
    const float* __restrict__ ow, float* __restrict__ partial)
{
    __shared__ float ps[256];
    const int kc = blockIdx.x;
    const int b  = blockIdx.y;
    const int t  = threadIdx.x;
    const int j  = kc * 256 + t;
    const int jj = (j < 2048) ? j : j - 2048;
    const int ii = 4 * b + (jj >> 9);
    const int e  = jj & 511;
    float v;
    if (j < 2048) {
        const float* bp = pmean + (size_t)ii * 4 * EE + e;
        v = (bp[0] + bp[512] + bp[1024] + bp[1536]) * (1.0f / 512.0f);
    } else {
        const float* bp = pmax + (size_t)ii * 4 * EE + e;
        v = fmaxf(fmaxf(bp[0], bp[512]), fmaxf(bp[1024], bp[1536]));
    }
    ps[t] = v;
    __syncthreads();
    f32x4 acc = {0.f, 0.f, 0.f, 0.f};
    const float* wp = ow + (size_t)kc * 256 * 1024 + t * 4;
#pragma unroll 8
    for (int q = 0; q < 256; ++q) {
        f32x4 w4 = *(const f32x4*)(wp + (size_t)q * 1024);
        float p = ps[q];
        acc[0] = fmaf(p, w4[0], acc[0]);
        acc[1] = fmaf(p, w4[1], acc[1]);
        acc[2] = fmaf(p, w4[2], acc[2]);
        acc[3] = fmaf(p, w4[3], acc[3]);
    }
    *(f32x4*)(partial + ((size_t)kc * 32 + b) * 1024 + t * 4) = acc;
}

// ---------------------------------------------------------------------------
// K5b: final reduce over 16 K-chunks + bias + relu.
// ---------------------------------------------------------------------------
__global__ __launch_bounds__(256) void k_out_final(
    const float* __restrict__ partial, const float* __restrict__ ob,
    float* __restrict__ out)
{
    const int idx = blockIdx.x * 256 + threadIdx.x;
    const int b = idx >> 10, o = idx & 1023;
    float s = ob[o];
#pragma unroll
    for (int kc = 0; kc < 16; ++kc)
        s += partial[((size_t)kc * 32 + b) * 1024 + o];
    out[idx] = fmaxf(s, 0.f);
}

// ---------------------------------------------------------------------------
extern "C" void kernel_launch(void* const* d_in, const int* in_sizes, int n_in,
                              void* d_out, int out_size, void* d_ws, size_t ws_size,
                              hipStream_t stream)
{
    const float* x1     = (const float*)d_in[0];
    const float* x2     = (const float*)d_in[1];
    const int*   x1_len = (const int*)d_in[2];
    const int*   x2_len = (const int*)d_in[3];
    const float* fw     = (const float*)d_in[4];
    const float* fb     = (const float*)d_in[5];
    const float* ow     = (const float*)d_in[6];
    const float* ob     = (const float*)d_in[7];

    float* out  = (float*)d_out;                  // [32, 1024]
    float* attn = out + (size_t)BATCH * 1024;     // [128, 512, 512] f32

    // workspace layout (~275 MB)
    char* wp = (char*)d_ws;
    unsigned short* x1bf   = (unsigned short*)wp; wp += (size_t)BATCH * LL * EE * 2;
    unsigned short* x2bf   = (unsigned short*)wp; wp += (size_t)NB * LL * EE * 2;
    unsigned short* x2t    = (unsigned short*)wp; wp += (size_t)NB * LL * EE * 2;
    unsigned short* Cbuf   = (unsigned short*)wp; wp += (size_t)NB * LL * 1024 * 2;
    unsigned short* fwt    = (unsigned short*)wp; wp += (size_t)EE * 1024 * 2;
    float* pmean   = (float*)wp; wp += (size_t)NB * 4 * EE * 4;
    float* pmax    = (float*)wp; wp += (size_t)NB * 4 * EE * 4;
    float* partial = (float*)wp; wp += (size_t)16 * BATCH * 1024 * 4;

    k_cvt_x1<<<dim3(BATCH * LL * EE / 4 / 256), 256, 0, stream>>>(x1, x1bf);
    k_cvt_x2<<<dim3(8, 8, NB), 256, 0, stream>>>(x2, x2bf, x2t);
    k_cvt_fw<<<dim3(8, 16), 256, 0, stream>>>(fw, fwt);
    k_attn<<<dim3(128, 4), 1024, 0, stream>>>(x1bf, x2bf, x2t, x1_len, x2_len, attn, Cbuf);
    k_fuse_mfma<<<dim3(128, 16), 256, 0, stream>>>(Cbuf, fwt, fb, pmean, pmax);
    k_out_split<<<dim3(16, BATCH), 256, 0, stream>>>(pmean, pmax, ow, partial);
    k_out_final<<<dim3(BATCH * 1024 / 256), 256, 0, stream>>>(partial, ob, out);
}

// Round 6
// 548.566 us; speedup vs baseline: 1.0610x; 1.0513x over previous
//
#include <hip/hip_runtime.h>
#include <cstddef>

// Problem constants (reference: B=32, NDOC=4, L=512, E=512)
#define BATCH 32
#define NB    128
#define LL    512
#define EE    512
#define SCALE 0.044194173824159216f
#define NEG_INF -1e9f

typedef __attribute__((ext_vector_type(4))) float f32x4;
typedef __attribute__((ext_vector_type(8))) short s16x8;          // 8 bf16 (4 VGPRs) MFMA frag
typedef __attribute__((ext_vector_type(4))) unsigned short u16x4;

// full fence (PV phase + one-time sync points)
#define STEP_FENCE() asm volatile("s_waitcnt vmcnt(0) lgkmcnt(0)\n\ts_barrier" ::: "memory")

__device__ __forceinline__ unsigned short f2b(float f) {          // f32 -> bf16 RNE
    unsigned u = __float_as_uint(f);
    u += 0x7FFFu + ((u >> 16) & 1u);
    return (unsigned short)(u >> 16);
}
__device__ __forceinline__ float b2f(unsigned short h) {
    return __uint_as_float(((unsigned)h) << 16);
}

// async global->LDS, 16B per lane. LDS dest = wave-uniform base + lane*16.
__device__ __forceinline__ void gld_lds16(const unsigned short* g, unsigned short* l) {
    __builtin_amdgcn_global_load_lds(
        (const __attribute__((address_space(1))) void*)g,
        (__attribute__((address_space(3))) void*)l, 16, 0, 0);
}

// ---------------------------------------------------------------------------
// Converters: x1 -> bf16; x2 -> bf16 (row) + bf16 transposed; fw -> fw^T bf16
// ---------------------------------------------------------------------------
__global__ __launch_bounds__(256) void k_cvt_x1(
    const float* __restrict__ x1, unsigned short* __restrict__ x1bf)
{
    const size_t idx = (size_t)blockIdx.x * 256 + threadIdx.x;
    f32x4 v = *(const f32x4*)(x1 + idx * 4);
    u16x4 o = { f2b(v[0]), f2b(v[1]), f2b(v[2]), f2b(v[3]) };
    *(u16x4*)(x1bf + idx * 4) = o;
}

__global__ __launch_bounds__(256) void k_cvt_x2(
    const float* __restrict__ x2,
    unsigned short* __restrict__ x2bf, unsigned short* __restrict__ x2t)
{
    __shared__ float T[64][65];
    const int i = blockIdx.z, kb = blockIdx.y * 64, eb = blockIdx.x * 64;
    const float* src = x2 + (size_t)i * LL * EE;
    unsigned short* db = x2bf + (size_t)i * LL * EE;
    unsigned short* dt = x2t  + (size_t)i * LL * EE;
    const int t = threadIdx.x, r16 = t >> 4, c4 = (t & 15) * 4;
#pragma unroll
    for (int p = 0; p < 4; ++p) {
        int row = p * 16 + r16;
        f32x4 v = *(const f32x4*)(src + (size_t)(kb + row) * EE + eb + c4);
        T[row][c4] = v[0]; T[row][c4+1] = v[1]; T[row][c4+2] = v[2]; T[row][c4+3] = v[3];
        u16x4 o = { f2b(v[0]), f2b(v[1]), f2b(v[2]), f2b(v[3]) };
        *(u16x4*)(db + (size_t)(kb + row) * EE + eb + c4) = o;
    }
    __syncthreads();
#pragma unroll
    for (int p = 0; p < 4; ++p) {
        int erow = p * 16 + r16;
        u16x4 o = { f2b(T[c4][erow]), f2b(T[c4+1][erow]),
                    f2b(T[c4+2][erow]), f2b(T[c4+3][erow]) };
        *(u16x4*)(dt + (size_t)(eb + erow) * LL + kb + c4) = o;   // dt[e][k]=src[k][e]
    }
}

// fw [1024][512] -> fwt[e][j'] bf16 with K-interleave j' = (j<512) ? 2j : 2(j-512)+1
// (matches Cbuf's interleaved [diff,prod] pair layout; GEMM result invariant).
__global__ __launch_bounds__(256) void k_cvt_fw(
    const float* __restrict__ fw, unsigned short* __restrict__ fwt)
{
    __shared__ float T[64][65];
    const int jb = blockIdx.y * 64, eb = blockIdx.x * 64;
    const int t = threadIdx.x, r16 = t >> 4, c4 = (t & 15) * 4;
#pragma unroll
    for (int p = 0; p < 4; ++p) {
        int row = p * 16 + r16;
        f32x4 v = *(const f32x4*)(fw + (size_t)(jb + row) * EE + eb + c4);
        T[row][c4] = v[0]; T[row][c4+1] = v[1]; T[row][c4+2] = v[2]; T[row][c4+3] = v[3];
    }
    __syncthreads();
#pragma unroll
    for (int p = 0; p < 4; ++p) {
        int erow = p * 16 + r16;
#pragma unroll
        for (int k = 0; k < 4; ++k) {
            int jold = jb + c4 + k;
            int jn = (jold < 512) ? (2 * jold) : (2 * (jold - 512) + 1);
            fwt[(size_t)(eb + erow) * 1024 + jn] = f2b(T[c4 + k][erow]);
        }
    }
}

// ---------------------------------------------------------------------------
// K1 (fused): scores GEMM -> in-block softmax -> PV GEMM.
// One block = one batch i x 128 q-rows x full k-range (512). 1024 thr, 160KB.
// Scores phase: TRUE counted 3-buffer pipeline (T3+T4): per step
//   {vmcnt(L) [L=own loads/stage, NOT 0]; s_barrier; issue stage(it+2);
//    ds_read buf[it%3]; MFMA} -- stage(it+1) stays IN FLIGHT across the
// barrier (>=1 full step latency coverage). vmcnt(0) only at last step.
// Safety: reads of step it-1 are lgkm-complete before each wave reaches
// barrier it; stage(it+2) (overwriting buf it-1) issues after that barrier.
// Uses raw s_barrier (NOT __syncthreads, which force-drains vmcnt(0)).
// PV phase: 2-buffer full-fence (no LDS room for a 3rd V buffer).
// XCD remap: flat=x+y*128 (512 blocks); xcd=flat&7; i=xcd*16+(idx>>2).
// LDS 160KB: [0,120K) scores 3x40KB staging, then P[128][512] swizzled at
// [0,128K) (time-disjoint); [128K,160K) softmax arrays, then PV V-dbuf.
// ---------------------------------------------------------------------------
__global__ __launch_bounds__(1024, 4) void k_attn(
    const unsigned short* __restrict__ x1bf,
    const unsigned short* __restrict__ x2bf,
    const unsigned short* __restrict__ x2t,
    const int* __restrict__ x1_len, const int* __restrict__ x2_len,
    float* __restrict__ attn, unsigned short* __restrict__ Cbuf)
{
    __shared__ __align__(16) char smem[163840];                 // 160 KB
    // scores staging: 3 slices of {A [128][32] 8KB | B [512][32] 32KB} = 40KB
    // P lives at smem[0..128K), swizzled; addressed via byte offsets.
    float* rowred = (float*)(smem + 131072);                    // [8][128] 4KB
    float* rowst  = (float*)(smem + 131072 + 4096);             // [128]
    unsigned short* Vst0 = (unsigned short*)(smem + 131072);    // [256][32] 16KB
    unsigned short* Vst1 = (unsigned short*)(smem + 147456);    // 16KB

    const int flat = blockIdx.x + blockIdx.y * 128;             // [0,512)
    const int xcd  = flat & 7;
    const int idx  = flat >> 3;                                 // [0,64)
    const int i    = xcd * 16 + (idx >> 2);
    const int q0   = (idx & 3) * 128;
    const unsigned short* Ag = x1bf + (size_t)(i & 31) * LL * EE;
    const unsigned short* Bg = x2bf + (size_t)i * LL * EE;
    const unsigned short* Vg = x2t  + (size_t)i * LL * EE;
    const int t = threadIdx.x, lane = t & 63;
    const int w = t >> 6;                                       // 16 waves
    const int m = lane & 15, quad = lane >> 4;
    const int lrow = lane >> 2, lcol = (lane & 3) * 8;
    const int wrow = w >> 3, wcol = w & 7;                      // scores: 2x8 waves

    f32x4 acc[4][4];
#pragma unroll
    for (int r = 0; r < 4; ++r)
#pragma unroll
        for (int c = 0; c < 4; ++c) acc[r][c] = (f32x4){0.f, 0.f, 0.f, 0.f};

    // ---- Phase 1: scores GEMM over e, counted 3-buffer pipeline ----
    // stage slice sl into buffer base (A then B; 3 loads for w<8, else 2)
#define STAGE_SCORES(sl, base)                                                          \
    do {                                                                                \
        unsigned short* An_ = (unsigned short*)(base);                                  \
        unsigned short* Bn_ = (unsigned short*)((char*)(base) + 8192);                  \
        const int e0_ = (sl) * 32;                                                      \
        if (w < 8)                                                                      \
            gld_lds16(Ag + (size_t)(q0 + w * 16 + lrow) * EE + e0_ + lcol, &An_[w * 512]); \
        gld_lds16(Bg + (size_t)((2 * w) * 16 + lrow) * EE + e0_ + lcol, &Bn_[(2 * w) * 512]); \
        gld_lds16(Bg + (size_t)((2 * w + 1) * 16 + lrow) * EE + e0_ + lcol, &Bn_[(2 * w + 1) * 512]); \
    } while (0)

    STAGE_SCORES(0, smem);
    STAGE_SCORES(1, smem + 40960);

#pragma unroll
    for (int it = 0; it < 16; ++it) {
        if (it == 15)   asm volatile("s_waitcnt vmcnt(0)" ::: "memory");
        else if (w < 8) asm volatile("s_waitcnt vmcnt(3)" ::: "memory");
        else            asm volatile("s_waitcnt vmcnt(2)" ::: "memory");
        __builtin_amdgcn_s_barrier();
        if (it < 14) STAGE_SCORES(it + 2, smem + 40960 * ((it + 2) % 3));
        char* cb = smem + 40960 * (it % 3);
        unsigned short* Ac = (unsigned short*)cb;
        unsigned short* Bc = (unsigned short*)(cb + 8192);
        s16x8 af[4], bfr[4];
#pragma unroll
        for (int rt = 0; rt < 4; ++rt)
            af[rt] = *(const s16x8*)&Ac[(wrow * 64 + rt * 16 + m) * 32 + quad * 8];
#pragma unroll
        for (int ct = 0; ct < 4; ++ct)
            bfr[ct] = *(const s16x8*)&Bc[(wcol * 64 + ct * 16 + m) * 32 + quad * 8];
#pragma unroll
        for (int rt = 0; rt < 4; ++rt)
#pragma unroll
            for (int ct = 0; ct < 4; ++ct)
                acc[rt][ct] = __builtin_amdgcn_mfma_f32_16x16x32_bf16(
                    af[rt], bfr[ct], acc[rt][ct], 0, 0, 0);
    }
    __syncthreads();                                           // staging done, lgkm drained

    const int qlen = x1_len[i & 31];
    const int klen = x2_len[i];

    // ---- mask + scale in place ----
#pragma unroll
    for (int rt = 0; rt < 4; ++rt)
#pragma unroll
        for (int reg = 0; reg < 4; ++reg) {
            const int l = q0 + wrow * 64 + rt * 16 + quad * 4 + reg;
            const bool qok = l < qlen;
#pragma unroll
            for (int ct = 0; ct < 4; ++ct) {
                const int k = wcol * 64 + ct * 16 + m;
                acc[rt][ct][reg] = (qok && k < klen) ? acc[rt][ct][reg] * SCALE : NEG_INF;
            }
        }

    // ---- row max: per-wave 64-col partial -> LDS -> 8-way reduce ----
#pragma unroll
    for (int rt = 0; rt < 4; ++rt)
#pragma unroll
        for (int reg = 0; reg < 4; ++reg) {
            float v = fmaxf(fmaxf(acc[rt][0][reg], acc[rt][1][reg]),
                            fmaxf(acc[rt][2][reg], acc[rt][3][reg]));
            v = fmaxf(v, __shfl_xor(v, 1));
            v = fmaxf(v, __shfl_xor(v, 2));
            v = fmaxf(v, __shfl_xor(v, 4));
            v = fmaxf(v, __shfl_xor(v, 8));
            if (m == 0)
                rowred[wcol * 128 + wrow * 64 + rt * 16 + quad * 4 + reg] = v;
        }
    __syncthreads();
    if (t < 128) {
        float mx = rowred[t];
#pragma unroll
        for (int c = 1; c < 8; ++c) mx = fmaxf(mx, rowred[c * 128 + t]);
        rowst[t] = mx;
    }
    __syncthreads();

    // ---- exp + row sum ----
#pragma unroll
    for (int rt = 0; rt < 4; ++rt)
#pragma unroll
        for (int reg = 0; reg < 4; ++reg) {
            const int lloc = wrow * 64 + rt * 16 + quad * 4 + reg;
            const float mx = rowst[lloc];
            float s = 0.f;
#pragma unroll
            for (int ct = 0; ct < 4; ++ct) {
                float p = __expf(acc[rt][ct][reg] - mx);
                acc[rt][ct][reg] = p;
                s += p;
            }
            s += __shfl_xor(s, 1);
            s += __shfl_xor(s, 2);
            s += __shfl_xor(s, 4);
            s += __shfl_xor(s, 8);
            if (m == 0) rowred[wcol * 128 + lloc] = s;
        }
    __syncthreads();
    if (t < 128) {
        float s = 0.f;
#pragma unroll
        for (int c = 0; c < 8; ++c) s += rowred[c * 128 + t];
        rowst[t] = 1.0f / s;
    }
    __syncthreads();

    // ---- normalize: write attn f32 (output) + P bf16 (LDS, swizzled) ----
    float* op = attn + (size_t)i * LL * LL;
#pragma unroll
    for (int rt = 0; rt < 4; ++rt)
#pragma unroll
        for (int reg = 0; reg < 4; ++reg) {
            const int lloc = wrow * 64 + rt * 16 + quad * 4 + reg;
            const float inv = rowst[lloc];
#pragma unroll
            for (int ct = 0; ct < 4; ++ct) {
                const int k = wcol * 64 + ct * 16 + m;
                float p = acc[rt][ct][reg] * inv;
                op[(size_t)(q0 + lloc) * LL + k] = p;
                unsigned off = (unsigned)(lloc * 1024 + k * 2) ^ (unsigned)((lloc & 7) << 4);
                *(unsigned short*)(smem + off) = f2b(p);
            }
        }
    __syncthreads();                                           // P complete; rowst dead

    // ---- Phase 2: PV GEMM, two e-halves of 256 (waves 4x4, fenced dbuf) ----
    const int pwr = w >> 2, pwc = w & 3;
    unsigned short* Cb = Cbuf + (size_t)i * LL * 1024;
#pragma unroll
    for (int eh = 0; eh < 2; ++eh) {
        f32x4 acc2[2][4];
#pragma unroll
        for (int r = 0; r < 2; ++r)
#pragma unroll
            for (int c = 0; c < 4; ++c) acc2[r][c] = (f32x4){0.f, 0.f, 0.f, 0.f};

        // prologue: stage kt=0 into V0 (1 load/thread: 16 wave-segs of 16 rows)
        gld_lds16(Vg + (size_t)(eh * 256 + w * 16 + lrow) * LL + lcol, &Vst0[w * 512]);
        STEP_FENCE();

        for (int kt = 0; kt < 16; ++kt) {
            const int k0 = kt * 32;
            unsigned short* Vc = (kt & 1) ? Vst1 : Vst0;
            if (kt < 15) {
                unsigned short* Vn = (kt & 1) ? Vst0 : Vst1;
                gld_lds16(Vg + (size_t)(eh * 256 + w * 16 + lrow) * LL + k0 + 32 + lcol,
                          &Vn[w * 512]);
            }
            s16x8 paf[2], pbf[4];
#pragma unroll
            for (int rt = 0; rt < 2; ++rt) {
                const int lr = pwr * 32 + rt * 16 + m;
                unsigned off = (unsigned)(lr * 1024 + (k0 + quad * 8) * 2)
                               ^ (unsigned)((lr & 7) << 4);
                paf[rt] = *(const s16x8*)(smem + off);
            }
#pragma unroll
            for (int ct = 0; ct < 4; ++ct)
                pbf[ct] = *(const s16x8*)&Vc[(pwc * 64 + ct * 16 + m) * 32 + quad * 8];
#pragma unroll
            for (int rt = 0; rt < 2; ++rt)
#pragma unroll
                for (int ct = 0; ct < 4; ++ct)
                    acc2[rt][ct] = __builtin_amdgcn_mfma_f32_16x16x32_bf16(
                        paf[rt], pbf[ct], acc2[rt][ct], 0, 0, 0);
            STEP_FENCE();
        }

        // epilogue: Cbuf[l][2e]=x1-att, [2e+1]=x1*att
#pragma unroll
        for (int rt = 0; rt < 2; ++rt)
#pragma unroll
            for (int reg = 0; reg < 4; ++reg) {
                const int l = q0 + pwr * 32 + rt * 16 + quad * 4 + reg;
#pragma unroll
                for (int ct = 0; ct < 4; ++ct) {
                    const int e = eh * 256 + pwc * 64 + ct * 16 + m;
                    float att = acc2[rt][ct][reg];
                    float xv  = b2f(Ag[(size_t)l * EE + e]);
                    unsigned pr = (unsigned)f2b(xv - att) | ((unsigned)f2b(xv * att) << 16);
                    *(unsigned*)(Cb + (size_t)l * 1024 + 2 * e) = pr;
                }
            }
    }
#undef STAGE_SCORES
}

// ---------------------------------------------------------------------------
// K4: fus = relu(Cbuf @ fw + b) with per-l-tile mean/max pooling partials.
// Counted 3-buffer pipeline (same mechanism as k_attn scores phase).
// LDS: 3 x {A 8KB | B 8KB} = 48KB + reduce arrays -> 3 blocks/CU.
// ---------------------------------------------------------------------------
__global__ __launch_bounds__(256) void k_fuse_mfma(
    const unsigned short* __restrict__ Cbuf,
    const unsigned short* __restrict__ fwt,
    const float* __restrict__ fb,
    float* __restrict__ pmean, float* __restrict__ pmax)
{
    __shared__ __align__(16) char fsm[49152];                  // 3 x 16KB
    __shared__ float psum[2][128];
    __shared__ float pmx[2][128];
    const int i  = blockIdx.x;
    const int lt = blockIdx.y >> 2;
    const int e0 = (blockIdx.y & 3) * 128;
    const unsigned short* Ab = Cbuf + ((size_t)i * LL + lt * 128) * 1024;
    const int t = threadIdx.x, lane = t & 63;
    const int w = t >> 6, wrow = w >> 1, wcol = w & 1;
    const int m = lane & 15, quad = lane >> 4;
    const int lrow = lane >> 2, lcol = (lane & 3) * 8;

    float bias[4];
#pragma unroll
    for (int ct = 0; ct < 4; ++ct) bias[ct] = fb[e0 + wcol * 64 + ct * 16 + m];
    float csum[4] = {0.f, 0.f, 0.f, 0.f};
    float cmax[4] = {-3e38f, -3e38f, -3e38f, -3e38f};

    f32x4 acc[4][4];
#pragma unroll
    for (int r = 0; r < 4; ++r)
#pragma unroll
        for (int c = 0; c < 4; ++c) acc[r][c] = (f32x4){0.f, 0.f, 0.f, 0.f};

#define STAGE_FUSE(sl, base)                                                            \
    do {                                                                                \
        unsigned short* Al_ = (unsigned short*)(base);                                  \
        unsigned short* Bl_ = (unsigned short*)((char*)(base) + 8192);                  \
        const int j0_ = (sl) * 32;                                                      \
        _Pragma("unroll")                                                               \
        for (int c_ = 0; c_ < 2; ++c_) {                                                \
            const int s_ = c_ * 4 + w;                                                  \
            gld_lds16(Ab + (size_t)(s_ * 16 + lrow) * 1024 + j0_ + lcol, &Al_[s_ * 512]); \
            gld_lds16(fwt + (size_t)(e0 + s_ * 16 + lrow) * 1024 + j0_ + lcol, &Bl_[s_ * 512]); \
        }                                                                               \
    } while (0)

    STAGE_FUSE(0, fsm);
    STAGE_FUSE(1, fsm + 16384);

#pragma unroll
    for (int it = 0; it < 32; ++it) {
        if (it == 31) asm volatile("s_waitcnt vmcnt(0)" ::: "memory");
        else          asm volatile("s_waitcnt vmcnt(4)" ::: "memory");
        __builtin_amdgcn_s_barrier();
        if (it < 30) STAGE_FUSE(it + 2, fsm + 16384 * ((it + 2) % 3));
        char* cb = fsm + 16384 * (it % 3);
        unsigned short* Ac = (unsigned short*)cb;
        unsigned short* Bc = (unsigned short*)(cb + 8192);
        s16x8 af[4], bfr[4];
#pragma unroll
        for (int rt = 0; rt < 4; ++rt)
            af[rt] = *(const s16x8*)&Ac[(wrow * 64 + rt * 16 + m) * 32 + quad * 8];
#pragma unroll
        for (int ct = 0; ct < 4; ++ct)
            bfr[ct] = *(const s16x8*)&Bc[(wcol * 64 + ct * 16 + m) * 32 + quad * 8];
#pragma unroll
        for (int rt = 0; rt < 4; ++rt)
#pragma unroll
            for (int ct = 0; ct < 4; ++ct)
                acc[rt][ct] = __builtin_amdgcn_mfma_f32_16x16x32_bf16(
                    af[rt], bfr[ct], acc[rt][ct], 0, 0, 0);
    }
#undef STAGE_FUSE
#pragma unroll
    for (int rt = 0; rt < 4; ++rt)
#pragma unroll
        for (int reg = 0; reg < 4; ++reg)
#pragma unroll
            for (int ct = 0; ct < 4; ++ct) {
                float f = fmaxf(acc[rt][ct][reg] + bias[ct], 0.f);
                csum[ct] += f;
                cmax[ct] = fmaxf(cmax[ct], f);
            }
#pragma unroll
    for (int ct = 0; ct < 4; ++ct) {
        csum[ct] += __shfl_xor(csum[ct], 16);
        csum[ct] += __shfl_xor(csum[ct], 32);
        cmax[ct] = fmaxf(cmax[ct], __shfl_xor(cmax[ct], 16));
        cmax[ct] = fmaxf(cmax[ct], __shfl_xor(cmax[ct], 32));
    }
    if (quad == 0) {
#pragma unroll
        for (int ct = 0; ct < 4; ++ct) {
            psum[wrow][wcol * 64 + ct * 16 + m] = csum[ct];
            pmx[wrow][wcol * 64 + ct * 16 + m] = cmax[ct];
        }
    }
    __syncthreads();
    if (t < 128) {
        float s  = psum[0][t] + psum[1][t];
        float mx = fmaxf(pmx[0][t], pmx[1][t]);
        pmean[((size_t)i * 4 + lt) * EE + e0 + t] = s;     // raw sum over 128 l's
        pmax[((size_t)i * 4 + lt) * EE + e0 + t]  = mx;
    }
}

// ---------------------------------------------------------------------------
// K5a: split-K partial GEMM for the output head; reduces the 4 l-tile pooling
// partials inline while loading the pooled vector.
// ---------------------------------------------------------------------------
__global__ __launch_bounds__(256) void k_out_split(
    const float* __restrict__ pmean, const float* __restrict__ pmax,
    const float* __restrict__ ow, float* __restrict__ partial)
{
    __shared__ float ps[256];
    const int kc = blockIdx.x;
    const int b  = blockIdx.y;
    const int t  = threadIdx.x;
    const int j  = kc * 256 + t;
    const int jj = (j < 2048) ? j : j - 2048;
    const int ii = 4 * b + (jj >> 9);
    const int e  = jj & 511;
    float v;
    if (j < 2048) {
        const float* bp = pmean + (size_t)ii * 4 * EE + e;
        v = (bp[0] + bp[512] + bp[1024] + bp[1536]) * (1.0f / 512.0f);
    } else {
        const float* bp = pmax + (size_t)ii * 4 * EE + e;
        v = fmaxf(fmaxf(bp[0], bp[512]), fmaxf(bp[1024], bp[1536]));
    }
    ps[t] = v;
    __syncthreads();
    f32x4 acc = {0.f, 0.f, 0.f, 0.f};
    const float* wp = ow + (size_t)kc * 256 * 1024 + t * 4;
#pragma unroll 8
    for (int q = 0; q < 256; ++q) {
        f32x4 w4 = *(const f32x4*)(wp + (size_t)q * 1024);
        float p = ps[q];
        acc[0] = fmaf(p, w4[0], acc[0]);
        acc[1] = fmaf(p, w4[1], acc[1]);
        acc[2] = fmaf(p, w4[2], acc[2]);
        acc[3] = fmaf(p, w4[3], acc[3]);
    }
    *(f32x4*)(partial + ((size_t)kc * 32 + b) * 1024 + t * 4) = acc;
}

// ---------------------------------------------------------------------------
// K5b: final reduce over 16 K-chunks + bias + relu.
// ---------------------------------------------------------------------------
__global__ __launch_bounds__(256) void k_out_final(
    const float* __restrict__ partial, const float* __restrict__ ob,
    float* __restrict__ out)
{
    const int idx = blockIdx.x * 256 + threadIdx.x;
    const int b = idx >> 10, o = idx & 1023;
    float s = ob[o];
#pragma unroll
    for (int kc = 0; kc < 16; ++kc)
        s += partial[((size_t)kc * 32 + b) * 1024 + o];
    out[idx] = fmaxf(s, 0.f);
}

// ---------------------------------------------------------------------------
extern "C" void kernel_launch(void* const* d_in, const int* in_sizes, int n_in,
                              void* d_out, int out_size, void* d_ws, size_t ws_size,
                              hipStream_t stream)
{
    const float* x1     = (const float*)d_in[0];
    const float* x2     = (const float*)d_in[1];
    const int*   x1_len = (const int*)d_in[2];
    const int*   x2_len = (const int*)d_in[3];
    const float* fw     = (const float*)d_in[4];
    const float* fb     = (const float*)d_in[5];
    const float* ow     = (const float*)d_in[6];
    const float* ob     = (const float*)d_in[7];

    float* out  = (float*)d_out;                  // [32, 1024]
    float* attn = out + (size_t)BATCH * 1024;     // [128, 512, 512] f32

    // workspace layout (~275 MB)
    char* wp = (char*)d_ws;
    unsigned short* x1bf   = (unsigned short*)wp; wp += (size_t)BATCH * LL * EE * 2;
    unsigned short* x2bf   = (unsigned short*)wp; wp += (size_t)NB * LL * EE * 2;
    unsigned short* x2t    = (unsigned short*)wp; wp += (size_t)NB * LL * EE * 2;
    unsigned short* Cbuf   = (unsigned short*)wp; wp += (size_t)NB * LL * 1024 * 2;
    unsigned short* fwt    = (unsigned short*)wp; wp += (size_t)EE * 1024 * 2;
    float* pmean   = (float*)wp; wp += (size_t)NB * 4 * EE * 4;
    float* pmax    = (float*)wp; wp += (size_t)NB * 4 * EE * 4;
    float* partial = (float*)wp; wp += (size_t)16 * BATCH * 1024 * 4;

    k_cvt_x1<<<dim3(BATCH * LL * EE / 4 / 256), 256, 0, stream>>>(x1, x1bf);
    k_cvt_x2<<<dim3(8, 8, NB), 256, 0, stream>>>(x2, x2bf, x2t);
    k_cvt_fw<<<dim3(8, 16), 256, 0, stream>>>(fw, fwt);
    k_attn<<<dim3(128, 4), 1024, 0, stream>>>(x1bf, x2bf, x2t, x1_len, x2_len, attn, Cbuf);
    k_fuse_mfma<<<dim3(128, 16), 256, 0, stream>>>(Cbuf, fwt, fb, pmean, pmax);
    k_out_split<<<dim3(16, BATCH), 256, 0, stream>>>(pmean, pmax, ow, partial);
    k_out_final<<<dim3(BATCH * 1024 / 256), 256, 0, stream>>>(partial, ob, out);
}